// Round 8
// baseline (201.642 us; speedup 1.0000x reference)
//
#include <hip/hip_runtime.h>

#define NP 8732
#define NQ (NP / 4)          // 2183 float4 chunks
#define NPT 35               // ceil(NP / 256) per-thread CE registers (fallback)
#define NSEL 36              // select kernel: 9 float4 per thread
#define NO 16
#define BLK 256
#define NWAVE (BLK / 64)
#define SPLIT 8
#define CHUNK ((NP + SPLIT - 1) / SPLIT)  // 1092; last chunk short (1088)
#define NITER ((CHUNK + BLK - 1) / BLK)   // 5

// ---------------------------------------------------------------------------
// Evidence log:
//  - One block/row is grid-limited to 2 blocks/CU (21% occupancy): latency
//    stalls dominate. Match phase split out at grid B*SPLIT fixed its half.
//  - BLK=512 regressed (barrier pile-up); launch_bounds cap below need
//    spills to scratch -- watch WRITE_SIZE.
//  - R8 (solo-thread priors + SGPR corners, predicated `if(ov)` body):
//    55.6 -> 47.9us, VGPR 36, WRITE 4.6MB. Best match version.
//  - R9 (ballot wave-skip): REGRESSED to 52.3us. Wave-skip dead end.
//  - R10 (pf[9] register prefetch + full unroll): CATASTROPHE 280us,
//    FETCH 500MB / WRITE 304MB scratch spill storm.
//  - R13: dropping the ov-guard ALSO spills (VGPR 36->64, WRITE 67.7MB,
//    100.6us). The `if (ov)` exec-mask form is the regalloc-stable form.
//    R14 revert confirmed: back to 47.5us / VGPR 36 / WRITE 4.6MB.
//  - R14 cross-round arithmetic: residual (total - match) is ~146us on BOTH
//    the loss_kernel path (R1: 194.6-47.9) and the ce+select path (R6:
//    193.1-47.5). CE extraction changed nothing => the histogram-select
//    phase (common to both) + fixed overhead IS the ~140us. select_kernel
//    is invisible in top-5 (just under match's 47.5).
//  - R15: SPLIT 4->8. (a) match occupancy 42%/VALUBusy 63% => latency not
//    covered; 2x blocks improves residency+tail. (b) diagnostic: match
//    dropping below select's duration forces select into the next top-5,
//    measuring the residual composition.
//  - R16: round-7 bench was another infra failure (container died twice,
//    same as round 4; R5 passed the identical source on retry). SPLIT=8
//    delta re-audited (short-chunk clamp, s_objc bounds, ws arithmetic,
//    ce_g alignment 575488%16==0) -- resubmitted unchanged.
//  - Ballot-aggregated histograms cost more VALU than conflicts saved.
// ---------------------------------------------------------------------------

__device__ __forceinline__ float rfl(float x) {
    return __uint_as_float(__builtin_amdgcn_readfirstlane(__float_as_uint(x)));
}

// Kernel A: match a CHUNK of priors vs all 16 objects. One thread per prior;
// object corners in SGPRs; predicated per-object guard (regalloc-stable form).
__global__ __launch_bounds__(BLK, 4) void match_kernel(
    const float* __restrict__ boxes,    // [B,O,4] cxcy
    const float* __restrict__ priors,   // [P,4]  cxcy
    unsigned char* __restrict__ g_obj,  // [B,NP]
    float* __restrict__ g_bv,           // [B,16,SPLIT]
    int*   __restrict__ g_bi)           // [B,16,SPLIT]
{
    const int b    = blockIdx.x;
    const int s    = blockIdx.y;
    const int tid  = threadIdx.x;
    const int lane = tid & 63;
    const int wv   = tid >> 6;
    const int lo = s * CHUNK;
    const int hi = (lo + CHUNK < NP) ? (lo + CHUNK) : NP;

    __shared__ float s_pv[NWAVE][NO][16];
    __shared__ int   s_pi[NWAVE][NO][16];

    // wave-uniform object data: corners -> SGPRs via readfirstlane
    float sx0[NO], sy0[NO], sx1[NO], sy1[NO], ra[NO];
    {
        const float4* bx4 = (const float4*)(boxes + (size_t)b * NO * 4);
#pragma unroll
        for (int j = 0; j < NO; j++) {
            float4 o = bx4[j];
            float hx = o.z * 0.5f, hy = o.w * 0.5f;
            sx0[j] = rfl(o.x - hx); sy0[j] = rfl(o.y - hy);
            sx1[j] = rfl(o.x + hx); sy1[j] = rfl(o.y + hy);
            ra[j]  = o.z * o.w;
        }
    }

    float tbv[NO]; int tbp[NO];
#pragma unroll
    for (int j = 0; j < NO; j++) { tbv[j] = -1.0f; tbp[j] = lo; }

    unsigned char* obj_row = g_obj + (size_t)b * NP;
    for (int k = 0; k < NITER; k++) {
        int p0 = lo + tid + k * BLK;
        bool valid = p0 < hi;
        int p = valid ? p0 : hi - 1;          // clamped duplicate: harmless,
                                              // (v,i) identical under tie rule
        float4 pr = ((const float4*)priors)[p];
        float px0 = pr.x - pr.z * 0.5f, py0 = pr.y - pr.w * 0.5f;
        float px1 = pr.x + pr.z * 0.5f, py1 = pr.y + pr.w * 0.5f;
        float areab = pr.z * pr.w;
        if (!valid) px0 = 4.0f;               // object corners <= ~1.3: every
                                              // overlap test fails for this lane
        float bv = -1.0f; int bo = 0;
#pragma unroll
        for (int j = 0; j < NO; j++) {
            bool ov = (sx1[j] >= px0) && (px1 >= sx0[j]) &&
                      (sy1[j] >= py0) && (py1 >= sy0[j]);
            if (ov) {   // exec-masked body; non-overlap pairs have iou==0
                float ix0 = fmaxf(sx0[j], px0);
                float iy0 = fmaxf(sy0[j], py0);
                float ix1 = fminf(sx1[j], px1);
                float iy1 = fminf(sy1[j], py1);
                float iw = fmaxf(ix1 - ix0, 0.0f);
                float ih = fmaxf(iy1 - iy0, 0.0f);
                float inter = iw * ih;
                float den = ra[j] + areab - inter;
                float iou = inter * __builtin_amdgcn_rcpf(den);
                if (iou > bv)     { bv = iou; bo = j; }        // first-wins over j
                if (iou > tbv[j]) { tbv[j] = iou; tbp[j] = p; } // first-wins over p
            }
        }
        if (valid) obj_row[p] = (unsigned char)(bo | ((bv >= 0.5f) ? 0x80 : 0));
    }

    // two-stage per-object block argmax reduction.
#pragma unroll
    for (int j = 0; j < NO; j++) {
        float v = tbv[j]; int i = tbp[j];
        float v2 = __shfl_down(v, 32, 64); int i2 = __shfl_down(i, 32, 64);
        if (v2 > v || (v2 == v && i2 < i)) { v = v2; i = i2; }
        v2 = __shfl_down(v, 16, 64); i2 = __shfl_down(i, 16, 64);
        if (v2 > v || (v2 == v && i2 < i)) { v = v2; i = i2; }
        if (lane < 16) { s_pv[wv][j][lane] = v; s_pi[wv][j][lane] = i; }
    }
    __syncthreads();
    {
        const int j = tid >> 4, e = tid & 15;
        float v = s_pv[0][j][e]; int i = s_pi[0][j][e];
#pragma unroll
        for (int w = 1; w < NWAVE; w++) {
            float v2 = s_pv[w][j][e]; int i2 = s_pi[w][j][e];
            if (v2 > v || (v2 == v && i2 < i)) { v = v2; i = i2; }
        }
#pragma unroll
        for (int off = 8; off >= 1; off >>= 1) {
            float v2 = __shfl_down(v, off, 16); int i2 = __shfl_down(i, off, 16);
            if (v2 > v || (v2 == v && i2 < i)) { v = v2; i = i2; }
        }
        if (e == 0) {
            g_bv[((size_t)b * NO + j) * SPLIT + s] = v;
            g_bi[((size_t)b * NO + j) * SPLIT + s] = i;
        }
    }
}

// Kernel B1: per-(row,chunk) CE + loc + conf_pos + npos at full parallelism.
// Streams CE values (0 for positives) to ce_g; writes per-chunk partials.
__global__ __launch_bounds__(BLK, 8) void ce_kernel(
    const float* __restrict__ plocs,    // [B,P,4]
    const float* __restrict__ pscores,  // [B,P,2]
    const float* __restrict__ boxes,    // [B,O,4]
    const float* __restrict__ priors,   // [P,4]
    const unsigned char* __restrict__ g_obj,
    const float* __restrict__ g_bv,
    const int*   __restrict__ g_bi,
    float* __restrict__ ce_g,           // [B,NP]
    float* __restrict__ loc_c,          // [B,SPLIT]
    float* __restrict__ conf_c,         // [B,SPLIT]
    int*   __restrict__ np_c)           // [B,SPLIT]
{
    const int b    = blockIdx.x;
    const int s    = blockIdx.y;
    const int tid  = threadIdx.x;
    const int lane = tid & 63;
    const int wv   = tid >> 6;
    const int lo = s * CHUNK;
    const int hi = (lo + CHUNK < NP) ? (lo + CHUNK) : NP;

    __shared__ unsigned char s_objc[CHUNK];
    __shared__ float s_bcw[NO][4];
    __shared__ int   s_bestp[NO];
    __shared__ float s_fred[2 * NWAVE];
    __shared__ int   s_ired[NWAVE];

    // chunk obj bytes (byte loads: lo%4 varies) + boxes + forced candidates
    const unsigned char* orow = g_obj + (size_t)b * NP + lo;
    for (int i = tid; i < hi - lo; i += BLK) s_objc[i] = orow[i];
    if (tid < NO * 4) ((float*)s_bcw)[tid] = boxes[(size_t)b * NO * 4 + tid];
    if (tid < NO) {
        // splits cover ascending p ranges; prefer-larger, then smaller idx
        const float* bv = g_bv + ((size_t)b * NO + tid) * SPLIT;
        const int*   bi = g_bi + ((size_t)b * NO + tid) * SPLIT;
        float v = bv[0]; int i = bi[0];
#pragma unroll
        for (int t = 1; t < SPLIT; t++) {
            float v2 = bv[t]; int i2 = bi[t];
            if (v2 > v || (v2 == v && i2 < i)) { v = v2; i = i2; }
        }
        s_bestp[tid] = i;
    }
    __syncthreads();
    if (tid == 0) {   // serial ascending: last o wins on duplicate priors
#pragma unroll
        for (int o = 0; o < NO; o++) {
            int p = s_bestp[o];
            if (p >= lo && p < hi) s_objc[p - lo] = (unsigned char)(0x80 | o);
        }
    }
    __syncthreads();

    float loc_sum = 0.0f, conf_pos = 0.0f; int np = 0;
    const float2* sc2 = (const float2*)(pscores + (size_t)b * NP * 2);
    const float4* pl4 = (const float4*)(plocs  + (size_t)b * NP * 4);
    float* cerow = ce_g + (size_t)b * NP;
    for (int p = lo + tid; p < hi; p += BLK) {
        unsigned m = s_objc[p - lo];
        bool pos = (m & 0x80) != 0;
        float2 sc = sc2[p];
        float mx = fmaxf(sc.x, sc.y);
        float dd = fabsf(sc.x - sc.y);
        float cev = mx + __logf(1.0f + __expf(-dd)) - (pos ? sc.y : sc.x);
        float v = 0.0f;
        if (pos) {
            np++;
            conf_pos += cev;
            int o = m & 15;
            float4 pr = ((const float4*)priors)[p];
            float gx = (s_bcw[o][0] - pr.x) / (pr.z / 10.0f);
            float gy = (s_bcw[o][1] - pr.y) / (pr.w / 10.0f);
            float gw = __logf(s_bcw[o][2] / pr.z) * 5.0f;
            float gh = __logf(s_bcw[o][3] / pr.w) * 5.0f;
            float4 pl = pl4[p];
            loc_sum += fabsf(pl.x - gx) + fabsf(pl.y - gy)
                     + fabsf(pl.z - gw) + fabsf(pl.w - gh);
        } else {
            v = cev;
        }
        cerow[p] = v;
    }

    int npw = np; float cw = conf_pos, lw = loc_sum;
    for (int off = 32; off; off >>= 1) {
        npw += __shfl_down(npw, off, 64);
        cw  += __shfl_down(cw, off, 64);
        lw  += __shfl_down(lw, off, 64);
    }
    if (lane == 0) { s_ired[wv] = npw; s_fred[wv] = cw; s_fred[NWAVE + wv] = lw; }
    __syncthreads();
    if (tid == 0) {
        int n = 0; float c = 0.0f, l = 0.0f;
#pragma unroll
        for (int w = 0; w < NWAVE; w++) { n += s_ired[w]; c += s_fred[w]; l += s_fred[NWAVE + w]; }
        np_c[b * SPLIT + s]   = n;
        conf_c[b * SPLIT + s] = c;
        loc_c[b * SPLIT + s]  = l;
    }
}

// Histogram bin selection over 4096 bins: find bin holding the kk-th largest
// (counting from the top); updates kk to the rank within the bin.
__device__ __forceinline__ int hist_select(unsigned* hist, unsigned* s_part,
                                           unsigned* s_csuf, unsigned* s_sel,
                                           unsigned& kk, int tid, int lane, int wv)
{
    unsigned ps = 0;
#pragma unroll
    for (int i = 0; i < 16; i++) ps += hist[tid * 16 + i];
    s_part[tid] = ps;
    __syncthreads();
    if (wv == 0) {
        unsigned c0 = s_part[4 * lane + 0], c1 = s_part[4 * lane + 1];
        unsigned c2 = s_part[4 * lane + 2], c3 = s_part[4 * lane + 3];
        unsigned g = c0 + c1 + c2 + c3;
        unsigned incl = g;
#pragma unroll
        for (int off = 1; off < 64; off <<= 1) {
            unsigned o = __shfl_down(incl, off, 64);
            if (lane + off < 64) incl += o;
        }
        unsigned excl = incl - g;           // count in chunks above this one
        s_csuf[4 * lane + 3] = excl;
        s_csuf[4 * lane + 2] = excl + c3;
        s_csuf[4 * lane + 1] = excl + c3 + c2;
        s_csuf[4 * lane + 0] = excl + c3 + c2 + c1;
    }
    __syncthreads();
    unsigned base = s_csuf[tid];            // count in bins >= 16*(tid+1)
    if (base < kk && kk <= base + s_part[tid]) {   // exactly one thread
        unsigned run = base;
        for (int i = 15; i >= 0; i--) {
            unsigned h = hist[tid * 16 + i];
            if (kk <= run + h) { s_sel[0] = (unsigned)(tid * 16 + i); s_sel[1] = kk - run; break; }
            run += h;
        }
    }
    __syncthreads();
    kk = s_sel[1];
    return (int)s_sel[0];
}

// Kernel B2: per-row top-K selection + hard-negative sum from precomputed CE.
// Padding zeros are inert: all negative CEs are > 0, so t > 0 and zeros never
// pass v > t; selAll adds them as +0.
__global__ __launch_bounds__(BLK, 2) void select_kernel(
    const float* __restrict__ ce_g,     // [B,NP]
    const int*   __restrict__ np_c,     // [B,SPLIT]
    float* __restrict__ chn_out)        // [B]  conf_hn per row
{
    const int b    = blockIdx.x;
    const int tid  = threadIdx.x;
    const int lane = tid & 63;
    const int wv   = tid >> 6;

    __shared__ unsigned s_hist[4096];
    __shared__ unsigned s_part[256];
    __shared__ unsigned s_csuf[256];
    __shared__ unsigned s_sel[2];
    __shared__ float s_tval;
    __shared__ float s_fred[NWAVE];
    __shared__ int   s_ired[NWAVE];

    // load the CE row: 9 float4 per thread, coalesced; pad with zeros
    float ce[NSEL];
    const float4* ce4 = (const float4*)(ce_g + (size_t)b * NP);
#pragma unroll
    for (int k = 0; k < 9; k++) {
        int q = tid + k * BLK;
        float4 v;
        if (q < NQ) v = ce4[q];
        else { v.x = 0.0f; v.y = 0.0f; v.z = 0.0f; v.w = 0.0f; }
        ce[4 * k + 0] = v.x; ce[4 * k + 1] = v.y;
        ce[4 * k + 2] = v.z; ce[4 * k + 3] = v.w;
    }

    int n_pos = 0;
#pragma unroll
    for (int t = 0; t < SPLIT; t++) n_pos += np_c[b * SPLIT + t];

    const int K = 3 * n_pos;
    const bool selAll = (K >= NP);
    float t = 0.0f;
    if (!selAll) {
        unsigned kk = (unsigned)K;
        // level 1: bits [30:19]
        for (int i = tid; i < 4096; i += BLK) s_hist[i] = 0u;
        __syncthreads();
#pragma unroll
        for (int k = 0; k < NSEL; k++)
            atomicAdd(&s_hist[__float_as_uint(ce[k]) >> 19], 1u);
        __syncthreads();
        unsigned b1 = (unsigned)hist_select(s_hist, s_part, s_csuf, s_sel, kk, tid, lane, wv);
        unsigned cnt1 = s_hist[b1];
        if (cnt1 == 1u) {
#pragma unroll
            for (int k = 0; k < NSEL; k++)
                if ((__float_as_uint(ce[k]) >> 19) == b1) s_tval = ce[k];
            __syncthreads();
            t = s_tval;
        } else {
            // level 2: bits [18:7]
            __syncthreads();
            for (int i = tid; i < 4096; i += BLK) s_hist[i] = 0u;
            __syncthreads();
#pragma unroll
            for (int k = 0; k < NSEL; k++) {
                unsigned u = __float_as_uint(ce[k]);
                if ((u >> 19) == b1) atomicAdd(&s_hist[(u >> 7) & 0xFFFu], 1u);
            }
            __syncthreads();
            unsigned b2 = (unsigned)hist_select(s_hist, s_part, s_csuf, s_sel, kk, tid, lane, wv);
            unsigned p2 = (b1 << 12) | b2;
            unsigned cnt2 = s_hist[b2];
            if (cnt2 == 1u) {
#pragma unroll
                for (int k = 0; k < NSEL; k++)
                    if ((__float_as_uint(ce[k]) >> 7) == p2) s_tval = ce[k];
                __syncthreads();
                t = s_tval;
            } else {
                // level 3: bits [6:0]
                __syncthreads();
                for (int i = tid; i < 4096; i += BLK) s_hist[i] = 0u;
                __syncthreads();
#pragma unroll
                for (int k = 0; k < NSEL; k++) {
                    unsigned u = __float_as_uint(ce[k]);
                    if ((u >> 7) == p2) atomicAdd(&s_hist[u & 0x7Fu], 1u);
                }
                __syncthreads();
                unsigned b3 = (unsigned)hist_select(s_hist, s_part, s_csuf, s_sel, kk, tid, lane, wv);
                t = __uint_as_float((p2 << 7) | b3);
            }
        }
    }

    // sum of top-K = sum(v > t) + (K - cnt_gt) * t  (exact under ties)
    float sgt = 0.0f; int cgt = 0;
#pragma unroll
    for (int k = 0; k < NSEL; k++) {
        float v = ce[k];
        if (selAll || v > t) { sgt += v; cgt++; }
    }

    float a = sgt; int g = cgt;
    for (int off = 32; off; off >>= 1) {
        a += __shfl_down(a, off, 64);
        g += __shfl_down(g, off, 64);
    }
    __syncthreads();
    if (lane == 0) { s_fred[wv] = a; s_ired[wv] = g; }
    __syncthreads();
    if (tid == 0) {
        float sa = 0.0f; int sg = 0;
#pragma unroll
        for (int w = 0; w < NWAVE; w++) { sa += s_fred[w]; sg += s_ired[w]; }
        chn_out[b] = selAll ? sa : (sa + (float)(K - sg) * t);
    }
}

__global__ __launch_bounds__(256) void mbox_finalize2_kernel(
    const float* __restrict__ loc_c, const float* __restrict__ conf_c,
    const int* __restrict__ np_c, const float* __restrict__ chn,
    int B, float* __restrict__ out)
{
    __shared__ float sl[4], sc[4];
    __shared__ int si[4];
    int tid = threadIdx.x, lane = tid & 63, wv = tid >> 6;
    float l = 0.0f, c = 0.0f; int n = 0;
    for (int i = tid; i < B * SPLIT; i += 256) {
        l += loc_c[i]; c += conf_c[i]; n += np_c[i];
    }
    for (int i = tid; i < B; i += 256) c += chn[i];
    for (int off = 32; off; off >>= 1) {
        l += __shfl_down(l, off, 64);
        c += __shfl_down(c, off, 64);
        n += __shfl_down(n, off, 64);
    }
    if (lane == 0) { sl[wv] = l; sc[wv] = c; si[wv] = n; }
    __syncthreads();
    if (tid == 0) {
        float tl = sl[0] + sl[1] + sl[2] + sl[3];
        float tc = sc[0] + sc[1] + sc[2] + sc[3];
        int tn = si[0] + si[1] + si[2] + si[3];
        float fn = (float)tn;
        out[0] = tc / fn + tl / (fn * 4.0f);
    }
}

// ------------------------- round-5 monolith (fallback if ws too small) -----
__global__ __launch_bounds__(BLK, 2) void mbox_row_kernel(
    const float* __restrict__ plocs, const float* __restrict__ pscores,
    const float* __restrict__ boxes, const float* __restrict__ priors,
    float* __restrict__ loc_out, float* __restrict__ conf_out,
    int* __restrict__ npos_out)
{
    const int b = blockIdx.x, tid = threadIdx.x, lane = tid & 63, wv = tid >> 6;
    const int par = tid & 1, objLo = par << 3;
    __shared__ __align__(16) float s_ce[NP];
    __shared__ unsigned char s_obj[NP];
    __shared__ float s_bcw[NO][4], s_bxy[NO][4], s_barea[NO];
    __shared__ float s_redv[NO * NWAVE]; __shared__ int s_redi[NO * NWAVE];
    __shared__ int s_bestp[NO];
    __shared__ unsigned s_hist16[16];
    __shared__ float s_tval;
    __shared__ float s_fred[3 * NWAVE]; __shared__ int s_ired[NWAVE];

    if (tid < NO * 4) ((float*)s_bcw)[tid] = boxes[(size_t)b * NO * 4 + tid];
    __syncthreads();
    if (tid < NO) {
        float cx = s_bcw[tid][0], cy = s_bcw[tid][1], w = s_bcw[tid][2], h = s_bcw[tid][3];
        s_bxy[tid][0] = cx - w * 0.5f; s_bxy[tid][1] = cy - h * 0.5f;
        s_bxy[tid][2] = cx + w * 0.5f; s_bxy[tid][3] = cy + h * 0.5f;
        s_barea[tid] = w * h;
    }
    __syncthreads();
    float rx0[8], ry0[8], rx1[8], ry1[8], ra[8];
#pragma unroll
    for (int j = 0; j < 8; j++) {
        rx0[j] = s_bxy[objLo + j][0]; ry0[j] = s_bxy[objLo + j][1];
        rx1[j] = s_bxy[objLo + j][2]; ry1[j] = s_bxy[objLo + j][3];
        ra[j]  = s_barea[objLo + j];
    }
    float tbv[8]; int tbp[8];
#pragma unroll
    for (int j = 0; j < 8; j++) { tbv[j] = -1.0f; tbp[j] = 0; }
    for (int p = (tid >> 1); p < NP; p += (BLK / 2)) {
        float4 pr = ((const float4*)priors)[p];
        float px0 = pr.x - pr.z * 0.5f, py0 = pr.y - pr.w * 0.5f;
        float px1 = pr.x + pr.z * 0.5f, py1 = pr.y + pr.w * 0.5f;
        float areab = pr.z * pr.w;
        float bv = -1.0f; int bo = objLo;
#pragma unroll
        for (int j = 0; j < 8; j++) {
            float ix0 = fmaxf(rx0[j], px0), iy0 = fmaxf(ry0[j], py0);
            float ix1 = fminf(rx1[j], px1), iy1 = fminf(ry1[j], py1);
            float iw = fmaxf(ix1 - ix0, 0.0f), ih = fmaxf(iy1 - iy0, 0.0f);
            float inter = iw * ih, den = ra[j] + areab - inter;
            float iou = inter * __builtin_amdgcn_rcpf(den);
            if (iou > bv) { bv = iou; bo = objLo + j; }
            if (iou > tbv[j]) { tbv[j] = iou; tbp[j] = p; }
        }
        float vN = __shfl_xor(bv, 1, 64); int oN = __shfl_xor(bo, 1, 64);
        bool take = par ? (vN >= bv) : (vN > bv);
        if (take) { bv = vN; bo = oN; }
        if (par == 0) s_obj[p] = (unsigned char)(bo | ((bv >= 0.5f) ? 0x80 : 0));
    }
#pragma unroll
    for (int j = 0; j < 8; j++) {
        float v = tbv[j]; int i = tbp[j];
        for (int off = 32; off >= 2; off >>= 1) {
            float v2 = __shfl_down(v, off, 64); int i2 = __shfl_down(i, off, 64);
            if (v2 > v || (v2 == v && i2 < i)) { v = v2; i = i2; }
        }
        if (lane < 2) { s_redv[(objLo + j) * NWAVE + wv] = v; s_redi[(objLo + j) * NWAVE + wv] = i; }
    }
    __syncthreads();
    if (tid < NO) {
        float v = s_redv[tid * NWAVE]; int i = s_redi[tid * NWAVE];
#pragma unroll
        for (int w = 1; w < NWAVE; w++) {
            float v2 = s_redv[tid * NWAVE + w]; int i2 = s_redi[tid * NWAVE + w];
            if (v2 > v || (v2 == v && i2 < i)) { v = v2; i = i2; }
        }
        s_bestp[tid] = i;
    }
    __syncthreads();
    if (tid == 0) {
#pragma unroll
        for (int o = 0; o < NO; o++) s_obj[s_bestp[o]] = (unsigned char)(0x80 | o);
    }
    __syncthreads();
    float loc_sum = 0.0f, conf_pos = 0.0f; int np = 0;
    const float2* sc2 = (const float2*)(pscores + (size_t)b * NP * 2);
    const float4* pl4 = (const float4*)(plocs + (size_t)b * NP * 4);
    for (int p = tid; p < NP; p += BLK) {
        unsigned m = s_obj[p]; bool pos = (m & 0x80) != 0;
        float2 s = sc2[p];
        float mx = fmaxf(s.x, s.y), dd = fabsf(s.x - s.y);
        float cev = mx + __logf(1.0f + __expf(-dd)) - (pos ? s.y : s.x);
        if (pos) {
            np++; conf_pos += cev;
            int o = m & 15;
            float4 pr = ((const float4*)priors)[p];
            float gx = (s_bcw[o][0] - pr.x) / (pr.z / 10.0f);
            float gy = (s_bcw[o][1] - pr.y) / (pr.w / 10.0f);
            float gw = __logf(s_bcw[o][2] / pr.z) * 5.0f;
            float gh = __logf(s_bcw[o][3] / pr.w) * 5.0f;
            float4 pl = pl4[p];
            loc_sum += fabsf(pl.x - gx) + fabsf(pl.y - gy) + fabsf(pl.z - gw) + fabsf(pl.w - gh);
            s_ce[p] = 0.0f;
        } else s_ce[p] = cev;
    }
    int npw = np;
    for (int off = 32; off; off >>= 1) npw += __shfl_down(npw, off, 64);
    if (lane == 0) s_ired[wv] = npw;
    __syncthreads();
    int n_pos = 0;
#pragma unroll
    for (int w = 0; w < NWAVE; w++) n_pos += s_ired[w];
    const int K = 3 * n_pos; const bool selAll = (K >= NP);
    float t = 0.0f;
    const float4* ce4 = (const float4*)s_ce;
    if (!selAll) {
        unsigned prefix = 0u, kk = (unsigned)K; bool done = false;
        for (int shift = 28; shift >= 0 && !done; shift -= 4) {
            __syncthreads();
            if (tid < 16) s_hist16[tid] = 0u;
            __syncthreads();
            unsigned maskhi = (shift == 28) ? 0u : (0xFFFFFFFFu << (shift + 4));
            for (int q = tid; q < NQ; q += BLK) {
                float4 v = ce4[q];
#pragma unroll
                for (int j = 0; j < 4; j++) {
                    unsigned u = __float_as_uint(j == 0 ? v.x : j == 1 ? v.y : j == 2 ? v.z : v.w);
                    if ((u & maskhi) == prefix) atomicAdd(&s_hist16[(u >> shift) & 15u], 1u);
                }
            }
            __syncthreads();
            int dsel = 15; unsigned cnt;
            for (;; dsel--) { cnt = s_hist16[dsel]; if (kk <= cnt || dsel == 0) break; kk -= cnt; }
            prefix |= ((unsigned)dsel << shift);
            if (shift > 0 && cnt == 1u) {
                unsigned mh = 0xFFFFFFFFu << shift;
                for (int q = tid; q < NQ; q += BLK) {
                    float4 v = ce4[q];
#pragma unroll
                    for (int j = 0; j < 4; j++) {
                        float f = (j == 0 ? v.x : j == 1 ? v.y : j == 2 ? v.z : v.w);
                        if ((__float_as_uint(f) & mh) == prefix) s_tval = f;
                    }
                }
                __syncthreads();
                t = s_tval; done = true;
            } else if (shift == 0) t = __uint_as_float(prefix);
        }
    }
    float sgt = 0.0f; int cgt = 0;
    for (int q = tid; q < NQ; q += BLK) {
        float4 v = ce4[q];
        if (selAll || v.x > t) { sgt += v.x; cgt++; }
        if (selAll || v.y > t) { sgt += v.y; cgt++; }
        if (selAll || v.z > t) { sgt += v.z; cgt++; }
        if (selAll || v.w > t) { sgt += v.w; cgt++; }
    }
    float a = sgt, c = conf_pos, l = loc_sum; int g = cgt;
    for (int off = 32; off; off >>= 1) {
        a += __shfl_down(a, off, 64); c += __shfl_down(c, off, 64);
        l += __shfl_down(l, off, 64); g += __shfl_down(g, off, 64);
    }
    __syncthreads();
    if (lane == 0) { s_fred[wv] = a; s_fred[NWAVE + wv] = c; s_fred[2 * NWAVE + wv] = l; s_ired[wv] = g; }
    __syncthreads();
    if (tid == 0) {
        float sa = 0, sc = 0, sl = 0; int sg = 0;
#pragma unroll
        for (int w = 0; w < NWAVE; w++) { sa += s_fred[w]; sc += s_fred[NWAVE + w]; sl += s_fred[2 * NWAVE + w]; sg += s_ired[w]; }
        float conf_hn = selAll ? sa : (sa + (float)(K - sg) * t);
        conf_out[b] = sc + conf_hn; loc_out[b] = sl; npos_out[b] = n_pos;
    }
}

__global__ __launch_bounds__(256) void mbox_finalize_kernel(
    const float* __restrict__ loc_in, const float* __restrict__ conf_in,
    const int* __restrict__ npos_in, int B, float* __restrict__ out)
{
    __shared__ float sl[4], sc[4];
    __shared__ int si[4];
    int tid = threadIdx.x, lane = tid & 63, wv = tid >> 6;
    float l = 0.0f, c = 0.0f; int n = 0;
    for (int i = tid; i < B; i += 256) { l += loc_in[i]; c += conf_in[i]; n += npos_in[i]; }
    for (int off = 32; off; off >>= 1) {
        l += __shfl_down(l, off, 64);
        c += __shfl_down(c, off, 64);
        n += __shfl_down(n, off, 64);
    }
    if (lane == 0) { sl[wv] = l; sc[wv] = c; si[wv] = n; }
    __syncthreads();
    if (tid == 0) {
        float tl = sl[0] + sl[1] + sl[2] + sl[3];
        float tc = sc[0] + sc[1] + sc[2] + sc[3];
        int tn = si[0] + si[1] + si[2] + si[3];
        float fn = (float)tn;
        out[0] = tc / fn + tl / (fn * 4.0f);
    }
}

extern "C" void kernel_launch(void* const* d_in, const int* in_sizes, int n_in,
                              void* d_out, int out_size, void* d_ws, size_t ws_size,
                              hipStream_t stream) {
    const float* plocs   = (const float*)d_in[0];
    const float* pscores = (const float*)d_in[1];
    const float* boxes   = (const float*)d_in[2];
    const float* priors  = (const float*)d_in[3];
    const int B = in_sizes[0] / (NP * 4);

    // main-path workspace layout (16B-aligned ce_g: offsets are exact)
    float* loc_c  = (float*)d_ws;                                  // B*SPLIT
    float* conf_c = loc_c + (size_t)B * SPLIT;                     // B*SPLIT
    int*   np_c   = (int*)(conf_c + (size_t)B * SPLIT);            // B*SPLIT
    float* chn_ws = (float*)(np_c + (size_t)B * SPLIT);            // B
    float* g_bv   = chn_ws + B;                                    // B*NO*SPLIT
    int*   g_bi   = (int*)(g_bv + (size_t)B * NO * SPLIT);         // B*NO*SPLIT
    float* ce_g   = (float*)(g_bi + (size_t)B * NO * SPLIT);       // B*NP
    unsigned char* g_obj = (unsigned char*)(ce_g + (size_t)B * NP);// B*NP
    size_t need = (size_t)B * SPLIT * 12 + (size_t)B * 4
                + (size_t)B * NO * SPLIT * 8 + (size_t)B * NP * 5;

    if (ws_size >= need) {
        match_kernel<<<dim3(B, SPLIT), BLK, 0, stream>>>(boxes, priors, g_obj, g_bv, g_bi);
        ce_kernel<<<dim3(B, SPLIT), BLK, 0, stream>>>(plocs, pscores, boxes, priors,
                                                      g_obj, g_bv, g_bi,
                                                      ce_g, loc_c, conf_c, np_c);
        select_kernel<<<B, BLK, 0, stream>>>(ce_g, np_c, chn_ws);
        mbox_finalize2_kernel<<<1, 256, 0, stream>>>(loc_c, conf_c, np_c, chn_ws,
                                                     B, (float*)d_out);
    } else {
        float* loc_ws  = (float*)d_ws;
        float* conf_ws = loc_ws + B;
        int*   np_ws   = (int*)(conf_ws + B);
        mbox_row_kernel<<<B, BLK, 0, stream>>>(plocs, pscores, boxes, priors,
                                               loc_ws, conf_ws, np_ws);
        mbox_finalize_kernel<<<1, 256, 0, stream>>>(loc_ws, conf_ws, np_ws, B, (float*)d_out);
    }
}

// Round 9
// 196.436 us; speedup vs baseline: 1.0265x; 1.0265x over previous
//
#include <hip/hip_runtime.h>

#define NP 8732
#define NQ (NP / 4)          // 2183 float4 chunks
#define NPT 35               // ceil(NP / 256) per-thread CE registers (fallback)
#define NO 16
#define BLK 256
#define NWAVE (BLK / 64)
#define SPLIT 4
#define CHUNK (NP / SPLIT)   // 2183 exactly
#define NITER ((CHUNK + BLK - 1) / BLK)   // 9
#define BLKS 1024            // select kernel block size (16 waves)
#define NWAVES (BLKS / 64)
#define NSEL2 12             // select: 3 float4 per thread (3*1024 >= 2183)

// ---------------------------------------------------------------------------
// Evidence log:
//  - R8 (solo-thread priors + SGPR corners, predicated `if(ov)` body):
//    55.6 -> 47.9us, VGPR 36, WRITE 4.6MB. Best match version.
//  - R9 ballot wave-skip: REGRESSED (52.3). R10 pf[] prefetch-unroll:
//    CATASTROPHE (280us spill storm). R13 no-ov-guard: spills too (100us).
//    The `if (ov)` exec-mask form is the regalloc-stable form. Keep it.
//  - R14: residual (total - match) ~146us across monolith AND split paths;
//    CE extraction changed nothing.
//  - R15 (SPLIT 4->8): match 47.5 -> 50.3us. FAILED: occupancy rose
//    (42->55%) but per-block fixed cost (obj setup + 16-obj epilogue)
//    doubled. SPLIT=4 is the match optimum. Reverted.
//  - R15 diagnostic: select STILL < 50us (invisible in top-5). Residual
//    stable 146+-5 over 5 configs. H1: select ~45-50us (2 blocks/CU,
//    serial hist phases, clustered-exponent LDS atomics). H2: fixed
//    launch/memset overhead. R17 tests H1: select at BLK=1024 -> full
//    32-wave/CU occupancy, 4x parallel hist/scan phases, ce[12] regs.
//    If total ~unchanged => H2; next step is kernel fusion.
//  - Ballot-aggregated histograms cost more VALU than conflicts saved.
// ---------------------------------------------------------------------------

__device__ __forceinline__ float rfl(float x) {
    return __uint_as_float(__builtin_amdgcn_readfirstlane(__float_as_uint(x)));
}

// Kernel A: match a CHUNK of priors vs all 16 objects. One thread per prior;
// object corners in SGPRs; predicated per-object guard (regalloc-stable form).
__global__ __launch_bounds__(BLK, 4) void match_kernel(
    const float* __restrict__ boxes,    // [B,O,4] cxcy
    const float* __restrict__ priors,   // [P,4]  cxcy
    unsigned char* __restrict__ g_obj,  // [B,NP]
    float* __restrict__ g_bv,           // [B,16,SPLIT]
    int*   __restrict__ g_bi)           // [B,16,SPLIT]
{
    const int b    = blockIdx.x;
    const int s    = blockIdx.y;
    const int tid  = threadIdx.x;
    const int lane = tid & 63;
    const int wv   = tid >> 6;
    const int lo = s * CHUNK, hi = lo + CHUNK;

    __shared__ float s_pv[NWAVE][NO][16];
    __shared__ int   s_pi[NWAVE][NO][16];

    // wave-uniform object data: corners -> SGPRs via readfirstlane
    float sx0[NO], sy0[NO], sx1[NO], sy1[NO], ra[NO];
    {
        const float4* bx4 = (const float4*)(boxes + (size_t)b * NO * 4);
#pragma unroll
        for (int j = 0; j < NO; j++) {
            float4 o = bx4[j];
            float hx = o.z * 0.5f, hy = o.w * 0.5f;
            sx0[j] = rfl(o.x - hx); sy0[j] = rfl(o.y - hy);
            sx1[j] = rfl(o.x + hx); sy1[j] = rfl(o.y + hy);
            ra[j]  = o.z * o.w;
        }
    }

    float tbv[NO]; int tbp[NO];
#pragma unroll
    for (int j = 0; j < NO; j++) { tbv[j] = -1.0f; tbp[j] = lo; }

    unsigned char* obj_row = g_obj + (size_t)b * NP;
    for (int k = 0; k < NITER; k++) {
        int p0 = lo + tid + k * BLK;
        bool valid = p0 < hi;
        int p = valid ? p0 : hi - 1;          // clamped duplicate: harmless,
                                              // (v,i) identical under tie rule
        float4 pr = ((const float4*)priors)[p];
        float px0 = pr.x - pr.z * 0.5f, py0 = pr.y - pr.w * 0.5f;
        float px1 = pr.x + pr.z * 0.5f, py1 = pr.y + pr.w * 0.5f;
        float areab = pr.z * pr.w;
        if (!valid) px0 = 4.0f;               // object corners <= ~1.3: every
                                              // overlap test fails for this lane
        float bv = -1.0f; int bo = 0;
#pragma unroll
        for (int j = 0; j < NO; j++) {
            bool ov = (sx1[j] >= px0) && (px1 >= sx0[j]) &&
                      (sy1[j] >= py0) && (py1 >= sy0[j]);
            if (ov) {   // exec-masked body; non-overlap pairs have iou==0
                float ix0 = fmaxf(sx0[j], px0);
                float iy0 = fmaxf(sy0[j], py0);
                float ix1 = fminf(sx1[j], px1);
                float iy1 = fminf(sy1[j], py1);
                float iw = fmaxf(ix1 - ix0, 0.0f);
                float ih = fmaxf(iy1 - iy0, 0.0f);
                float inter = iw * ih;
                float den = ra[j] + areab - inter;
                float iou = inter * __builtin_amdgcn_rcpf(den);
                if (iou > bv)     { bv = iou; bo = j; }        // first-wins over j
                if (iou > tbv[j]) { tbv[j] = iou; tbp[j] = p; } // first-wins over p
            }
        }
        if (valid) obj_row[p] = (unsigned char)(bo | ((bv >= 0.5f) ? 0x80 : 0));
    }

    // two-stage per-object block argmax reduction.
#pragma unroll
    for (int j = 0; j < NO; j++) {
        float v = tbv[j]; int i = tbp[j];
        float v2 = __shfl_down(v, 32, 64); int i2 = __shfl_down(i, 32, 64);
        if (v2 > v || (v2 == v && i2 < i)) { v = v2; i = i2; }
        v2 = __shfl_down(v, 16, 64); i2 = __shfl_down(i, 16, 64);
        if (v2 > v || (v2 == v && i2 < i)) { v = v2; i = i2; }
        if (lane < 16) { s_pv[wv][j][lane] = v; s_pi[wv][j][lane] = i; }
    }
    __syncthreads();
    {
        const int j = tid >> 4, e = tid & 15;
        float v = s_pv[0][j][e]; int i = s_pi[0][j][e];
#pragma unroll
        for (int w = 1; w < NWAVE; w++) {
            float v2 = s_pv[w][j][e]; int i2 = s_pi[w][j][e];
            if (v2 > v || (v2 == v && i2 < i)) { v = v2; i = i2; }
        }
#pragma unroll
        for (int off = 8; off >= 1; off >>= 1) {
            float v2 = __shfl_down(v, off, 16); int i2 = __shfl_down(i, off, 16);
            if (v2 > v || (v2 == v && i2 < i)) { v = v2; i = i2; }
        }
        if (e == 0) {
            g_bv[((size_t)b * NO + j) * SPLIT + s] = v;
            g_bi[((size_t)b * NO + j) * SPLIT + s] = i;
        }
    }
}

// Kernel B1: per-(row,chunk) CE + loc + conf_pos + npos at full parallelism.
// Streams CE values (0 for positives) to ce_g; writes per-chunk partials.
__global__ __launch_bounds__(BLK, 8) void ce_kernel(
    const float* __restrict__ plocs,    // [B,P,4]
    const float* __restrict__ pscores,  // [B,P,2]
    const float* __restrict__ boxes,    // [B,O,4]
    const float* __restrict__ priors,   // [P,4]
    const unsigned char* __restrict__ g_obj,
    const float* __restrict__ g_bv,
    const int*   __restrict__ g_bi,
    float* __restrict__ ce_g,           // [B,NP]
    float* __restrict__ loc_c,          // [B,SPLIT]
    float* __restrict__ conf_c,         // [B,SPLIT]
    int*   __restrict__ np_c)           // [B,SPLIT]
{
    const int b    = blockIdx.x;
    const int s    = blockIdx.y;
    const int tid  = threadIdx.x;
    const int lane = tid & 63;
    const int wv   = tid >> 6;
    const int lo = s * CHUNK, hi = lo + CHUNK;

    __shared__ unsigned char s_objc[CHUNK];
    __shared__ float s_bcw[NO][4];
    __shared__ int   s_bestp[NO];
    __shared__ float s_fred[2 * NWAVE];
    __shared__ int   s_ired[NWAVE];

    // chunk obj bytes (byte loads: lo%4 varies) + boxes + forced candidates
    const unsigned char* orow = g_obj + (size_t)b * NP + lo;
    for (int i = tid; i < CHUNK; i += BLK) s_objc[i] = orow[i];
    if (tid < NO * 4) ((float*)s_bcw)[tid] = boxes[(size_t)b * NO * 4 + tid];
    if (tid < NO) {
        // splits cover ascending p ranges; prefer-larger, then smaller idx
        const float* bv = g_bv + ((size_t)b * NO + tid) * SPLIT;
        const int*   bi = g_bi + ((size_t)b * NO + tid) * SPLIT;
        float v = bv[0]; int i = bi[0];
#pragma unroll
        for (int t = 1; t < SPLIT; t++) {
            float v2 = bv[t]; int i2 = bi[t];
            if (v2 > v || (v2 == v && i2 < i)) { v = v2; i = i2; }
        }
        s_bestp[tid] = i;
    }
    __syncthreads();
    if (tid == 0) {   // serial ascending: last o wins on duplicate priors
#pragma unroll
        for (int o = 0; o < NO; o++) {
            int p = s_bestp[o];
            if (p >= lo && p < hi) s_objc[p - lo] = (unsigned char)(0x80 | o);
        }
    }
    __syncthreads();

    float loc_sum = 0.0f, conf_pos = 0.0f; int np = 0;
    const float2* sc2 = (const float2*)(pscores + (size_t)b * NP * 2);
    const float4* pl4 = (const float4*)(plocs  + (size_t)b * NP * 4);
    float* cerow = ce_g + (size_t)b * NP;
    for (int p = lo + tid; p < hi; p += BLK) {
        unsigned m = s_objc[p - lo];
        bool pos = (m & 0x80) != 0;
        float2 sc = sc2[p];
        float mx = fmaxf(sc.x, sc.y);
        float dd = fabsf(sc.x - sc.y);
        float cev = mx + __logf(1.0f + __expf(-dd)) - (pos ? sc.y : sc.x);
        float v = 0.0f;
        if (pos) {
            np++;
            conf_pos += cev;
            int o = m & 15;
            float4 pr = ((const float4*)priors)[p];
            float gx = (s_bcw[o][0] - pr.x) / (pr.z / 10.0f);
            float gy = (s_bcw[o][1] - pr.y) / (pr.w / 10.0f);
            float gw = __logf(s_bcw[o][2] / pr.z) * 5.0f;
            float gh = __logf(s_bcw[o][3] / pr.w) * 5.0f;
            float4 pl = pl4[p];
            loc_sum += fabsf(pl.x - gx) + fabsf(pl.y - gy)
                     + fabsf(pl.z - gw) + fabsf(pl.w - gh);
        } else {
            v = cev;
        }
        cerow[p] = v;
    }

    int npw = np; float cw = conf_pos, lw = loc_sum;
    for (int off = 32; off; off >>= 1) {
        npw += __shfl_down(npw, off, 64);
        cw  += __shfl_down(cw, off, 64);
        lw  += __shfl_down(lw, off, 64);
    }
    if (lane == 0) { s_ired[wv] = npw; s_fred[wv] = cw; s_fred[NWAVE + wv] = lw; }
    __syncthreads();
    if (tid == 0) {
        int n = 0; float c = 0.0f, l = 0.0f;
#pragma unroll
        for (int w = 0; w < NWAVE; w++) { n += s_ired[w]; c += s_fred[w]; l += s_fred[NWAVE + w]; }
        np_c[b * SPLIT + s]   = n;
        conf_c[b * SPLIT + s] = c;
        loc_c[b * SPLIT + s]  = l;
    }
}

// Histogram bin selection over 4096 bins (256-thread scan structure; threads
// >= 256 just participate in barriers). Finds bin holding the kk-th largest;
// updates kk to the rank within the bin.
__device__ __forceinline__ int hist_select(unsigned* hist, unsigned* s_part,
                                           unsigned* s_csuf, unsigned* s_sel,
                                           unsigned& kk, int tid, int lane, int wv)
{
    if (tid < 256) {
        unsigned ps = 0;
#pragma unroll
        for (int i = 0; i < 16; i++) ps += hist[tid * 16 + i];
        s_part[tid] = ps;
    }
    __syncthreads();
    if (wv == 0) {
        unsigned c0 = s_part[4 * lane + 0], c1 = s_part[4 * lane + 1];
        unsigned c2 = s_part[4 * lane + 2], c3 = s_part[4 * lane + 3];
        unsigned g = c0 + c1 + c2 + c3;
        unsigned incl = g;
#pragma unroll
        for (int off = 1; off < 64; off <<= 1) {
            unsigned o = __shfl_down(incl, off, 64);
            if (lane + off < 64) incl += o;
        }
        unsigned excl = incl - g;           // count in chunks above this one
        s_csuf[4 * lane + 3] = excl;
        s_csuf[4 * lane + 2] = excl + c3;
        s_csuf[4 * lane + 1] = excl + c3 + c2;
        s_csuf[4 * lane + 0] = excl + c3 + c2 + c1;
    }
    __syncthreads();
    if (tid < 256) {
        unsigned base = s_csuf[tid];        // count in bins >= 16*(tid+1)
        if (base < kk && kk <= base + s_part[tid]) {   // exactly one thread
            unsigned run = base;
            for (int i = 15; i >= 0; i--) {
                unsigned h = hist[tid * 16 + i];
                if (kk <= run + h) { s_sel[0] = (unsigned)(tid * 16 + i); s_sel[1] = kk - run; break; }
                run += h;
            }
        }
    }
    __syncthreads();
    kk = s_sel[1];
    return (int)s_sel[0];
}

// Kernel B2: per-row top-K selection + hard-negative sum from precomputed CE.
// BLK=1024: full 32-wave/CU occupancy at 2 blocks/CU; 3 float4 per thread.
// Padding zeros are inert: all negative CEs are > 0, so t > 0 and zeros never
// pass v > t; selAll adds them as +0.
__global__ __launch_bounds__(BLKS, 8) void select_kernel(
    const float* __restrict__ ce_g,     // [B,NP]
    const int*   __restrict__ np_c,     // [B,SPLIT]
    float* __restrict__ chn_out)        // [B]  conf_hn per row
{
    const int b    = blockIdx.x;
    const int tid  = threadIdx.x;
    const int lane = tid & 63;
    const int wv   = tid >> 6;

    __shared__ unsigned s_hist[4096];
    __shared__ unsigned s_part[256];
    __shared__ unsigned s_csuf[256];
    __shared__ unsigned s_sel[2];
    __shared__ float s_tval;
    __shared__ float s_fred[NWAVES];
    __shared__ int   s_ired[NWAVES];

    // load the CE row: 3 float4 per thread, coalesced; pad with zeros
    float ce[NSEL2];
    const float4* ce4 = (const float4*)(ce_g + (size_t)b * NP);
#pragma unroll
    for (int k = 0; k < 3; k++) {
        int q = tid + k * BLKS;
        float4 v;
        if (q < NQ) v = ce4[q];
        else { v.x = 0.0f; v.y = 0.0f; v.z = 0.0f; v.w = 0.0f; }
        ce[4 * k + 0] = v.x; ce[4 * k + 1] = v.y;
        ce[4 * k + 2] = v.z; ce[4 * k + 3] = v.w;
    }

    int n_pos = 0;
#pragma unroll
    for (int t = 0; t < SPLIT; t++) n_pos += np_c[b * SPLIT + t];

    const int K = 3 * n_pos;
    const bool selAll = (K >= NP);
    float t = 0.0f;
    if (!selAll) {
        unsigned kk = (unsigned)K;
        // level 1: bits [30:19]
        for (int i = tid; i < 4096; i += BLKS) s_hist[i] = 0u;
        __syncthreads();
#pragma unroll
        for (int k = 0; k < NSEL2; k++)
            atomicAdd(&s_hist[__float_as_uint(ce[k]) >> 19], 1u);
        __syncthreads();
        unsigned b1 = (unsigned)hist_select(s_hist, s_part, s_csuf, s_sel, kk, tid, lane, wv);
        unsigned cnt1 = s_hist[b1];
        if (cnt1 == 1u) {
#pragma unroll
            for (int k = 0; k < NSEL2; k++)
                if ((__float_as_uint(ce[k]) >> 19) == b1) s_tval = ce[k];
            __syncthreads();
            t = s_tval;
        } else {
            // level 2: bits [18:7]
            __syncthreads();
            for (int i = tid; i < 4096; i += BLKS) s_hist[i] = 0u;
            __syncthreads();
#pragma unroll
            for (int k = 0; k < NSEL2; k++) {
                unsigned u = __float_as_uint(ce[k]);
                if ((u >> 19) == b1) atomicAdd(&s_hist[(u >> 7) & 0xFFFu], 1u);
            }
            __syncthreads();
            unsigned b2 = (unsigned)hist_select(s_hist, s_part, s_csuf, s_sel, kk, tid, lane, wv);
            unsigned p2 = (b1 << 12) | b2;
            unsigned cnt2 = s_hist[b2];
            if (cnt2 == 1u) {
#pragma unroll
                for (int k = 0; k < NSEL2; k++)
                    if ((__float_as_uint(ce[k]) >> 7) == p2) s_tval = ce[k];
                __syncthreads();
                t = s_tval;
            } else {
                // level 3: bits [6:0]
                __syncthreads();
                for (int i = tid; i < 4096; i += BLKS) s_hist[i] = 0u;
                __syncthreads();
#pragma unroll
                for (int k = 0; k < NSEL2; k++) {
                    unsigned u = __float_as_uint(ce[k]);
                    if ((u >> 7) == p2) atomicAdd(&s_hist[u & 0x7Fu], 1u);
                }
                __syncthreads();
                unsigned b3 = (unsigned)hist_select(s_hist, s_part, s_csuf, s_sel, kk, tid, lane, wv);
                t = __uint_as_float((p2 << 7) | b3);
            }
        }
    }

    // sum of top-K = sum(v > t) + (K - cnt_gt) * t  (exact under ties)
    float sgt = 0.0f; int cgt = 0;
#pragma unroll
    for (int k = 0; k < NSEL2; k++) {
        float v = ce[k];
        if (selAll || v > t) { sgt += v; cgt++; }
    }

    float a = sgt; int g = cgt;
    for (int off = 32; off; off >>= 1) {
        a += __shfl_down(a, off, 64);
        g += __shfl_down(g, off, 64);
    }
    __syncthreads();
    if (lane == 0) { s_fred[wv] = a; s_ired[wv] = g; }
    __syncthreads();
    if (tid == 0) {
        float sa = 0.0f; int sg = 0;
#pragma unroll
        for (int w = 0; w < NWAVES; w++) { sa += s_fred[w]; sg += s_ired[w]; }
        chn_out[b] = selAll ? sa : (sa + (float)(K - sg) * t);
    }
}

__global__ __launch_bounds__(256) void mbox_finalize2_kernel(
    const float* __restrict__ loc_c, const float* __restrict__ conf_c,
    const int* __restrict__ np_c, const float* __restrict__ chn,
    int B, float* __restrict__ out)
{
    __shared__ float sl[4], sc[4];
    __shared__ int si[4];
    int tid = threadIdx.x, lane = tid & 63, wv = tid >> 6;
    float l = 0.0f, c = 0.0f; int n = 0;
    for (int i = tid; i < B * SPLIT; i += 256) {
        l += loc_c[i]; c += conf_c[i]; n += np_c[i];
    }
    for (int i = tid; i < B; i += 256) c += chn[i];
    for (int off = 32; off; off >>= 1) {
        l += __shfl_down(l, off, 64);
        c += __shfl_down(c, off, 64);
        n += __shfl_down(n, off, 64);
    }
    if (lane == 0) { sl[wv] = l; sc[wv] = c; si[wv] = n; }
    __syncthreads();
    if (tid == 0) {
        float tl = sl[0] + sl[1] + sl[2] + sl[3];
        float tc = sc[0] + sc[1] + sc[2] + sc[3];
        int tn = si[0] + si[1] + si[2] + si[3];
        float fn = (float)tn;
        out[0] = tc / fn + tl / (fn * 4.0f);
    }
}

// ------------------------- round-5 monolith (fallback if ws too small) -----
__global__ __launch_bounds__(BLK, 2) void mbox_row_kernel(
    const float* __restrict__ plocs, const float* __restrict__ pscores,
    const float* __restrict__ boxes, const float* __restrict__ priors,
    float* __restrict__ loc_out, float* __restrict__ conf_out,
    int* __restrict__ npos_out)
{
    const int b = blockIdx.x, tid = threadIdx.x, lane = tid & 63, wv = tid >> 6;
    const int par = tid & 1, objLo = par << 3;
    __shared__ __align__(16) float s_ce[NP];
    __shared__ unsigned char s_obj[NP];
    __shared__ float s_bcw[NO][4], s_bxy[NO][4], s_barea[NO];
    __shared__ float s_redv[NO * NWAVE]; __shared__ int s_redi[NO * NWAVE];
    __shared__ int s_bestp[NO];
    __shared__ unsigned s_hist16[16];
    __shared__ float s_tval;
    __shared__ float s_fred[3 * NWAVE]; __shared__ int s_ired[NWAVE];

    if (tid < NO * 4) ((float*)s_bcw)[tid] = boxes[(size_t)b * NO * 4 + tid];
    __syncthreads();
    if (tid < NO) {
        float cx = s_bcw[tid][0], cy = s_bcw[tid][1], w = s_bcw[tid][2], h = s_bcw[tid][3];
        s_bxy[tid][0] = cx - w * 0.5f; s_bxy[tid][1] = cy - h * 0.5f;
        s_bxy[tid][2] = cx + w * 0.5f; s_bxy[tid][3] = cy + h * 0.5f;
        s_barea[tid] = w * h;
    }
    __syncthreads();
    float rx0[8], ry0[8], rx1[8], ry1[8], ra[8];
#pragma unroll
    for (int j = 0; j < 8; j++) {
        rx0[j] = s_bxy[objLo + j][0]; ry0[j] = s_bxy[objLo + j][1];
        rx1[j] = s_bxy[objLo + j][2]; ry1[j] = s_bxy[objLo + j][3];
        ra[j]  = s_barea[objLo + j];
    }
    float tbv[8]; int tbp[8];
#pragma unroll
    for (int j = 0; j < 8; j++) { tbv[j] = -1.0f; tbp[j] = 0; }
    for (int p = (tid >> 1); p < NP; p += (BLK / 2)) {
        float4 pr = ((const float4*)priors)[p];
        float px0 = pr.x - pr.z * 0.5f, py0 = pr.y - pr.w * 0.5f;
        float px1 = pr.x + pr.z * 0.5f, py1 = pr.y + pr.w * 0.5f;
        float areab = pr.z * pr.w;
        float bv = -1.0f; int bo = objLo;
#pragma unroll
        for (int j = 0; j < 8; j++) {
            float ix0 = fmaxf(rx0[j], px0), iy0 = fmaxf(ry0[j], py0);
            float ix1 = fminf(rx1[j], px1), iy1 = fminf(ry1[j], py1);
            float iw = fmaxf(ix1 - ix0, 0.0f), ih = fmaxf(iy1 - iy0, 0.0f);
            float inter = iw * ih, den = ra[j] + areab - inter;
            float iou = inter * __builtin_amdgcn_rcpf(den);
            if (iou > bv) { bv = iou; bo = objLo + j; }
            if (iou > tbv[j]) { tbv[j] = iou; tbp[j] = p; }
        }
        float vN = __shfl_xor(bv, 1, 64); int oN = __shfl_xor(bo, 1, 64);
        bool take = par ? (vN >= bv) : (vN > bv);
        if (take) { bv = vN; bo = oN; }
        if (par == 0) s_obj[p] = (unsigned char)(bo | ((bv >= 0.5f) ? 0x80 : 0));
    }
#pragma unroll
    for (int j = 0; j < 8; j++) {
        float v = tbv[j]; int i = tbp[j];
        for (int off = 32; off >= 2; off >>= 1) {
            float v2 = __shfl_down(v, off, 64); int i2 = __shfl_down(i, off, 64);
            if (v2 > v || (v2 == v && i2 < i)) { v = v2; i = i2; }
        }
        if (lane < 2) { s_redv[(objLo + j) * NWAVE + wv] = v; s_redi[(objLo + j) * NWAVE + wv] = i; }
    }
    __syncthreads();
    if (tid < NO) {
        float v = s_redv[tid * NWAVE]; int i = s_redi[tid * NWAVE];
#pragma unroll
        for (int w = 1; w < NWAVE; w++) {
            float v2 = s_redv[tid * NWAVE + w]; int i2 = s_redi[tid * NWAVE + w];
            if (v2 > v || (v2 == v && i2 < i)) { v = v2; i = i2; }
        }
        s_bestp[tid] = i;
    }
    __syncthreads();
    if (tid == 0) {
#pragma unroll
        for (int o = 0; o < NO; o++) s_obj[s_bestp[o]] = (unsigned char)(0x80 | o);
    }
    __syncthreads();
    float loc_sum = 0.0f, conf_pos = 0.0f; int np = 0;
    const float2* sc2 = (const float2*)(pscores + (size_t)b * NP * 2);
    const float4* pl4 = (const float4*)(plocs + (size_t)b * NP * 4);
    for (int p = tid; p < NP; p += BLK) {
        unsigned m = s_obj[p]; bool pos = (m & 0x80) != 0;
        float2 s = sc2[p];
        float mx = fmaxf(s.x, s.y), dd = fabsf(s.x - s.y);
        float cev = mx + __logf(1.0f + __expf(-dd)) - (pos ? s.y : s.x);
        if (pos) {
            np++; conf_pos += cev;
            int o = m & 15;
            float4 pr = ((const float4*)priors)[p];
            float gx = (s_bcw[o][0] - pr.x) / (pr.z / 10.0f);
            float gy = (s_bcw[o][1] - pr.y) / (pr.w / 10.0f);
            float gw = __logf(s_bcw[o][2] / pr.z) * 5.0f;
            float gh = __logf(s_bcw[o][3] / pr.w) * 5.0f;
            float4 pl = pl4[p];
            loc_sum += fabsf(pl.x - gx) + fabsf(pl.y - gy) + fabsf(pl.z - gw) + fabsf(pl.w - gh);
            s_ce[p] = 0.0f;
        } else s_ce[p] = cev;
    }
    int npw = np;
    for (int off = 32; off; off >>= 1) npw += __shfl_down(npw, off, 64);
    if (lane == 0) s_ired[wv] = npw;
    __syncthreads();
    int n_pos = 0;
#pragma unroll
    for (int w = 0; w < NWAVE; w++) n_pos += s_ired[w];
    const int K = 3 * n_pos; const bool selAll = (K >= NP);
    float t = 0.0f;
    const float4* ce4 = (const float4*)s_ce;
    if (!selAll) {
        unsigned prefix = 0u, kk = (unsigned)K; bool done = false;
        for (int shift = 28; shift >= 0 && !done; shift -= 4) {
            __syncthreads();
            if (tid < 16) s_hist16[tid] = 0u;
            __syncthreads();
            unsigned maskhi = (shift == 28) ? 0u : (0xFFFFFFFFu << (shift + 4));
            for (int q = tid; q < NQ; q += BLK) {
                float4 v = ce4[q];
#pragma unroll
                for (int j = 0; j < 4; j++) {
                    unsigned u = __float_as_uint(j == 0 ? v.x : j == 1 ? v.y : j == 2 ? v.z : v.w);
                    if ((u & maskhi) == prefix) atomicAdd(&s_hist16[(u >> shift) & 15u], 1u);
                }
            }
            __syncthreads();
            int dsel = 15; unsigned cnt;
            for (;; dsel--) { cnt = s_hist16[dsel]; if (kk <= cnt || dsel == 0) break; kk -= cnt; }
            prefix |= ((unsigned)dsel << shift);
            if (shift > 0 && cnt == 1u) {
                unsigned mh = 0xFFFFFFFFu << shift;
                for (int q = tid; q < NQ; q += BLK) {
                    float4 v = ce4[q];
#pragma unroll
                    for (int j = 0; j < 4; j++) {
                        float f = (j == 0 ? v.x : j == 1 ? v.y : j == 2 ? v.z : v.w);
                        if ((__float_as_uint(f) & mh) == prefix) s_tval = f;
                    }
                }
                __syncthreads();
                t = s_tval; done = true;
            } else if (shift == 0) t = __uint_as_float(prefix);
        }
    }
    float sgt = 0.0f; int cgt = 0;
    for (int q = tid; q < NQ; q += BLK) {
        float4 v = ce4[q];
        if (selAll || v.x > t) { sgt += v.x; cgt++; }
        if (selAll || v.y > t) { sgt += v.y; cgt++; }
        if (selAll || v.z > t) { sgt += v.z; cgt++; }
        if (selAll || v.w > t) { sgt += v.w; cgt++; }
    }
    float a = sgt, c = conf_pos, l = loc_sum; int g = cgt;
    for (int off = 32; off; off >>= 1) {
        a += __shfl_down(a, off, 64); c += __shfl_down(c, off, 64);
        l += __shfl_down(l, off, 64); g += __shfl_down(g, off, 64);
    }
    __syncthreads();
    if (lane == 0) { s_fred[wv] = a; s_fred[NWAVE + wv] = c; s_fred[2 * NWAVE + wv] = l; s_ired[wv] = g; }
    __syncthreads();
    if (tid == 0) {
        float sa = 0, sc = 0, sl = 0; int sg = 0;
#pragma unroll
        for (int w = 0; w < NWAVE; w++) { sa += s_fred[w]; sc += s_fred[NWAVE + w]; sl += s_fred[2 * NWAVE + w]; sg += s_ired[w]; }
        float conf_hn = selAll ? sa : (sa + (float)(K - sg) * t);
        conf_out[b] = sc + conf_hn; loc_out[b] = sl; npos_out[b] = n_pos;
    }
}

__global__ __launch_bounds__(256) void mbox_finalize_kernel(
    const float* __restrict__ loc_in, const float* __restrict__ conf_in,
    const int* __restrict__ npos_in, int B, float* __restrict__ out)
{
    __shared__ float sl[4], sc[4];
    __shared__ int si[4];
    int tid = threadIdx.x, lane = tid & 63, wv = tid >> 6;
    float l = 0.0f, c = 0.0f; int n = 0;
    for (int i = tid; i < B; i += 256) { l += loc_in[i]; c += conf_in[i]; n += npos_in[i]; }
    for (int off = 32; off; off >>= 1) {
        l += __shfl_down(l, off, 64);
        c += __shfl_down(c, off, 64);
        n += __shfl_down(n, off, 64);
    }
    if (lane == 0) { sl[wv] = l; sc[wv] = c; si[wv] = n; }
    __syncthreads();
    if (tid == 0) {
        float tl = sl[0] + sl[1] + sl[2] + sl[3];
        float tc = sc[0] + sc[1] + sc[2] + sc[3];
        int tn = si[0] + si[1] + si[2] + si[3];
        float fn = (float)tn;
        out[0] = tc / fn + tl / (fn * 4.0f);
    }
}

extern "C" void kernel_launch(void* const* d_in, const int* in_sizes, int n_in,
                              void* d_out, int out_size, void* d_ws, size_t ws_size,
                              hipStream_t stream) {
    const float* plocs   = (const float*)d_in[0];
    const float* pscores = (const float*)d_in[1];
    const float* boxes   = (const float*)d_in[2];
    const float* priors  = (const float*)d_in[3];
    const int B = in_sizes[0] / (NP * 4);

    // main-path workspace layout (16B-aligned ce_g: offsets are exact)
    float* loc_c  = (float*)d_ws;                                  // B*SPLIT
    float* conf_c = loc_c + (size_t)B * SPLIT;                     // B*SPLIT
    int*   np_c   = (int*)(conf_c + (size_t)B * SPLIT);            // B*SPLIT
    float* chn_ws = (float*)(np_c + (size_t)B * SPLIT);            // B
    float* g_bv   = chn_ws + B;                                    // B*NO*SPLIT
    int*   g_bi   = (int*)(g_bv + (size_t)B * NO * SPLIT);         // B*NO*SPLIT
    float* ce_g   = (float*)(g_bi + (size_t)B * NO * SPLIT);       // B*NP
    unsigned char* g_obj = (unsigned char*)(ce_g + (size_t)B * NP);// B*NP
    size_t need = (size_t)B * SPLIT * 12 + (size_t)B * 4
                + (size_t)B * NO * SPLIT * 8 + (size_t)B * NP * 5;

    if (ws_size >= need) {
        match_kernel<<<dim3(B, SPLIT), BLK, 0, stream>>>(boxes, priors, g_obj, g_bv, g_bi);
        ce_kernel<<<dim3(B, SPLIT), BLK, 0, stream>>>(plocs, pscores, boxes, priors,
                                                      g_obj, g_bv, g_bi,
                                                      ce_g, loc_c, conf_c, np_c);
        select_kernel<<<B, BLKS, 0, stream>>>(ce_g, np_c, chn_ws);
        mbox_finalize2_kernel<<<1, 256, 0, stream>>>(loc_c, conf_c, np_c, chn_ws,
                                                     B, (float*)d_out);
    } else {
        float* loc_ws  = (float*)d_ws;
        float* conf_ws = loc_ws + B;
        int*   np_ws   = (int*)(conf_ws + B);
        mbox_row_kernel<<<B, BLK, 0, stream>>>(plocs, pscores, boxes, priors,
                                               loc_ws, conf_ws, np_ws);
        mbox_finalize_kernel<<<1, 256, 0, stream>>>(loc_ws, conf_ws, np_ws, B, (float*)d_out);
    }
}

// Round 10
// 178.385 us; speedup vs baseline: 1.1304x; 1.1012x over previous
//
#include <hip/hip_runtime.h>

#define NP 8732
#define NQ (NP / 4)          // 2183 float4 chunks
#define NPT 35               // fallback monolith: ceil(NP/256)
#define NO 16
#define BLK 256
#define NWAVE (BLK / 64)
#define SPLIT 4
#define CHUNK (NP / SPLIT)   // 2183 exactly
#define NITER ((CHUNK + BLK - 1) / BLK)   // 9
#define BLKS 1024            // fused loss kernel block size (16 waves)
#define NWAVES (BLKS / 64)
#define NPT2 9               // fused: ceil(NP / 1024) per-thread CE registers

// ---------------------------------------------------------------------------
// Evidence log:
//  - R8 (solo-thread priors + SGPR corners, predicated `if(ov)` body):
//    55.6 -> 47.9us, VGPR 36, WRITE 4.6MB. Best match version.
//  - R9 ballot wave-skip REGRESSED; R10 pf[] prefetch-unroll CATASTROPHE
//    (spill storm); R13 no-ov-guard spills too. `if (ov)` exec-mask form is
//    the regalloc-stable form. Keep it. SPLIT=4 is the match optimum (R15:
//    SPLIT=8 cost more in per-block epilogue than occupancy bought).
//  - R14: residual (total - match) ~146us across monolith AND split paths.
//  - R17 (select at BLK=1024): inconclusive -- container clocks ~17% lower
//    (match 57us on identical code, hbm_gbps 116->96). LESSON: cross-
//    container deltas <10% are noise; compare hbm_gbps to detect slow
//    containers. select still <56us (invisible).
//  - R18: stop inferring the residual; structurally remove it. Fuse
//    ce+select into loss2_kernel (grid B, BLK=1024, 32 waves/CU): kills
//    ce_g 18MB roundtrip + one launch; CE in ce[9] registers feeds the
//    4096-bin select directly. R1-monolith FP pairing (absmax 0.0).
//  - Ballot-aggregated histograms cost more VALU than conflicts saved.
// ---------------------------------------------------------------------------

__device__ __forceinline__ float rfl(float x) {
    return __uint_as_float(__builtin_amdgcn_readfirstlane(__float_as_uint(x)));
}

// Kernel A: match a CHUNK of priors vs all 16 objects. One thread per prior;
// object corners in SGPRs; predicated per-object guard (regalloc-stable form).
__global__ __launch_bounds__(BLK, 4) void match_kernel(
    const float* __restrict__ boxes,    // [B,O,4] cxcy
    const float* __restrict__ priors,   // [P,4]  cxcy
    unsigned char* __restrict__ g_obj,  // [B,NP]
    float* __restrict__ g_bv,           // [B,16,SPLIT]
    int*   __restrict__ g_bi)           // [B,16,SPLIT]
{
    const int b    = blockIdx.x;
    const int s    = blockIdx.y;
    const int tid  = threadIdx.x;
    const int lane = tid & 63;
    const int wv   = tid >> 6;
    const int lo = s * CHUNK, hi = lo + CHUNK;

    __shared__ float s_pv[NWAVE][NO][16];
    __shared__ int   s_pi[NWAVE][NO][16];

    // wave-uniform object data: corners -> SGPRs via readfirstlane
    float sx0[NO], sy0[NO], sx1[NO], sy1[NO], ra[NO];
    {
        const float4* bx4 = (const float4*)(boxes + (size_t)b * NO * 4);
#pragma unroll
        for (int j = 0; j < NO; j++) {
            float4 o = bx4[j];
            float hx = o.z * 0.5f, hy = o.w * 0.5f;
            sx0[j] = rfl(o.x - hx); sy0[j] = rfl(o.y - hy);
            sx1[j] = rfl(o.x + hx); sy1[j] = rfl(o.y + hy);
            ra[j]  = o.z * o.w;
        }
    }

    float tbv[NO]; int tbp[NO];
#pragma unroll
    for (int j = 0; j < NO; j++) { tbv[j] = -1.0f; tbp[j] = lo; }

    unsigned char* obj_row = g_obj + (size_t)b * NP;
    for (int k = 0; k < NITER; k++) {
        int p0 = lo + tid + k * BLK;
        bool valid = p0 < hi;
        int p = valid ? p0 : hi - 1;          // clamped duplicate: harmless,
                                              // (v,i) identical under tie rule
        float4 pr = ((const float4*)priors)[p];
        float px0 = pr.x - pr.z * 0.5f, py0 = pr.y - pr.w * 0.5f;
        float px1 = pr.x + pr.z * 0.5f, py1 = pr.y + pr.w * 0.5f;
        float areab = pr.z * pr.w;
        if (!valid) px0 = 4.0f;               // object corners <= ~1.3: every
                                              // overlap test fails for this lane
        float bv = -1.0f; int bo = 0;
#pragma unroll
        for (int j = 0; j < NO; j++) {
            bool ov = (sx1[j] >= px0) && (px1 >= sx0[j]) &&
                      (sy1[j] >= py0) && (py1 >= sy0[j]);
            if (ov) {   // exec-masked body; non-overlap pairs have iou==0
                float ix0 = fmaxf(sx0[j], px0);
                float iy0 = fmaxf(sy0[j], py0);
                float ix1 = fminf(sx1[j], px1);
                float iy1 = fminf(sy1[j], py1);
                float iw = fmaxf(ix1 - ix0, 0.0f);
                float ih = fmaxf(iy1 - iy0, 0.0f);
                float inter = iw * ih;
                float den = ra[j] + areab - inter;
                float iou = inter * __builtin_amdgcn_rcpf(den);
                if (iou > bv)     { bv = iou; bo = j; }        // first-wins over j
                if (iou > tbv[j]) { tbv[j] = iou; tbp[j] = p; } // first-wins over p
            }
        }
        if (valid) obj_row[p] = (unsigned char)(bo | ((bv >= 0.5f) ? 0x80 : 0));
    }

    // two-stage per-object block argmax reduction.
#pragma unroll
    for (int j = 0; j < NO; j++) {
        float v = tbv[j]; int i = tbp[j];
        float v2 = __shfl_down(v, 32, 64); int i2 = __shfl_down(i, 32, 64);
        if (v2 > v || (v2 == v && i2 < i)) { v = v2; i = i2; }
        v2 = __shfl_down(v, 16, 64); i2 = __shfl_down(i, 16, 64);
        if (v2 > v || (v2 == v && i2 < i)) { v = v2; i = i2; }
        if (lane < 16) { s_pv[wv][j][lane] = v; s_pi[wv][j][lane] = i; }
    }
    __syncthreads();
    {
        const int j = tid >> 4, e = tid & 15;
        float v = s_pv[0][j][e]; int i = s_pi[0][j][e];
#pragma unroll
        for (int w = 1; w < NWAVE; w++) {
            float v2 = s_pv[w][j][e]; int i2 = s_pi[w][j][e];
            if (v2 > v || (v2 == v && i2 < i)) { v = v2; i = i2; }
        }
#pragma unroll
        for (int off = 8; off >= 1; off >>= 1) {
            float v2 = __shfl_down(v, off, 16); int i2 = __shfl_down(i, off, 16);
            if (v2 > v || (v2 == v && i2 < i)) { v = v2; i = i2; }
        }
        if (e == 0) {
            g_bv[((size_t)b * NO + j) * SPLIT + s] = v;
            g_bi[((size_t)b * NO + j) * SPLIT + s] = i;
        }
    }
}

// Histogram bin selection over 4096 bins (256-thread scan structure; threads
// >= 256 participate only in barriers). Finds bin holding the kk-th largest;
// updates kk to the rank within the bin.
__device__ __forceinline__ int hist_select(unsigned* hist, unsigned* s_part,
                                           unsigned* s_csuf, unsigned* s_sel,
                                           unsigned& kk, int tid, int lane, int wv)
{
    if (tid < 256) {
        unsigned ps = 0;
#pragma unroll
        for (int i = 0; i < 16; i++) ps += hist[tid * 16 + i];
        s_part[tid] = ps;
    }
    __syncthreads();
    if (wv == 0) {
        unsigned c0 = s_part[4 * lane + 0], c1 = s_part[4 * lane + 1];
        unsigned c2 = s_part[4 * lane + 2], c3 = s_part[4 * lane + 3];
        unsigned g = c0 + c1 + c2 + c3;
        unsigned incl = g;
#pragma unroll
        for (int off = 1; off < 64; off <<= 1) {
            unsigned o = __shfl_down(incl, off, 64);
            if (lane + off < 64) incl += o;
        }
        unsigned excl = incl - g;           // count in chunks above this one
        s_csuf[4 * lane + 3] = excl;
        s_csuf[4 * lane + 2] = excl + c3;
        s_csuf[4 * lane + 1] = excl + c3 + c2;
        s_csuf[4 * lane + 0] = excl + c3 + c2 + c1;
    }
    __syncthreads();
    if (tid < 256) {
        unsigned base = s_csuf[tid];        // count in bins >= 16*(tid+1)
        if (base < kk && kk <= base + s_part[tid]) {   // exactly one thread
            unsigned run = base;
            for (int i = 15; i >= 0; i--) {
                unsigned h = hist[tid * 16 + i];
                if (kk <= run + h) { s_sel[0] = (unsigned)(tid * 16 + i); s_sel[1] = kk - run; break; }
                run += h;
            }
        }
    }
    __syncthreads();
    kk = s_sel[1];
    return (int)s_sel[0];
}

// Kernel B (fused): per-row CE + loc + conf_pos + npos + top-K selection in
// one kernel. grid B x BLKS=1024 (32 waves/CU at 2 blocks/CU). CE lives in
// ce[9] registers; no ce_g roundtrip. Padding zeros inert (CE>0 => t>0).
__global__ __launch_bounds__(BLKS, 8) void loss2_kernel(
    const float* __restrict__ plocs,    // [B,P,4]
    const float* __restrict__ pscores,  // [B,P,2]
    const float* __restrict__ boxes,    // [B,O,4]
    const float* __restrict__ priors,   // [P,4]
    const unsigned char* __restrict__ g_obj,
    const float* __restrict__ g_bv,
    const int*   __restrict__ g_bi,
    float* __restrict__ loc_out,        // [B]
    float* __restrict__ conf_out,       // [B]
    int*   __restrict__ npos_out)       // [B]
{
    const int b    = blockIdx.x;
    const int tid  = threadIdx.x;
    const int lane = tid & 63;
    const int wv   = tid >> 6;

    __shared__ unsigned char s_obj[NP];
    __shared__ unsigned s_hist[4096];
    __shared__ unsigned s_part[256];
    __shared__ unsigned s_csuf[256];
    __shared__ unsigned s_sel[2];
    __shared__ float s_bcw[NO][4];
    __shared__ int   s_bestp[NO];
    __shared__ float s_tval;
    __shared__ float s_fred[3 * NWAVES];
    __shared__ int   s_ired[NWAVES];

    // obj row (coalesced word loads) + boxes + forced-prior candidates
    const unsigned* objw = (const unsigned*)(g_obj + (size_t)b * NP);
    for (int i = tid; i < NP / 4; i += BLKS) ((unsigned*)s_obj)[i] = objw[i];
    if (tid < NO * 4) ((float*)s_bcw)[tid] = boxes[(size_t)b * NO * 4 + tid];
    if (tid < NO) {
        // splits cover ascending p ranges; prefer-larger, then smaller idx
        const float* bv = g_bv + ((size_t)b * NO + tid) * SPLIT;
        const int*   bi = g_bi + ((size_t)b * NO + tid) * SPLIT;
        float v = bv[0]; int i = bi[0];
#pragma unroll
        for (int s = 1; s < SPLIT; s++) {
            float v2 = bv[s]; int i2 = bi[s];
            if (v2 > v || (v2 == v && i2 < i)) { v = v2; i = i2; }
        }
        s_bestp[tid] = i;
    }
    __syncthreads();
    if (tid == 0) {   // serial ascending: last o wins on duplicate priors
#pragma unroll
        for (int o = 0; o < NO; o++) s_obj[s_bestp[o]] = (unsigned char)(0x80 | o);
    }
    __syncthreads();

    // CE for all priors (registers), loc L1 for positives
    float ce[NPT2];
    float loc_sum = 0.0f, conf_pos = 0.0f; int np = 0;
    const float2* sc2 = (const float2*)(pscores + (size_t)b * NP * 2);
    const float4* pl4 = (const float4*)(plocs  + (size_t)b * NP * 4);
#pragma unroll
    for (int k = 0; k < NPT2; k++) {
        int p = tid + k * BLKS;
        float v = 0.0f;
        if (p < NP) {
            unsigned m = s_obj[p];
            bool pos = (m & 0x80) != 0;
            float2 s = sc2[p];
            float mx = fmaxf(s.x, s.y);
            float dd = fabsf(s.x - s.y);
            float cev = mx + __logf(1.0f + __expf(-dd)) - (pos ? s.y : s.x);
            if (pos) {
                np++;
                conf_pos += cev;
                int o = m & 15;
                float4 pr = ((const float4*)priors)[p];
                float gx = (s_bcw[o][0] - pr.x) / (pr.z / 10.0f);
                float gy = (s_bcw[o][1] - pr.y) / (pr.w / 10.0f);
                float gw = __logf(s_bcw[o][2] / pr.z) * 5.0f;
                float gh = __logf(s_bcw[o][3] / pr.w) * 5.0f;
                float4 pl = pl4[p];
                loc_sum += fabsf(pl.x - gx) + fabsf(pl.y - gy)
                         + fabsf(pl.z - gw) + fabsf(pl.w - gh);
            } else {
                v = cev;
            }
        }
        ce[k] = v;
    }

    int npw = np;
    for (int off = 32; off; off >>= 1) npw += __shfl_down(npw, off, 64);
    if (lane == 0) s_ired[wv] = npw;
    __syncthreads();
    int n_pos = 0;
#pragma unroll
    for (int w = 0; w < NWAVES; w++) n_pos += s_ired[w];

    // select K-th largest CE: up to 3 histogram levels over bits [30:19],
    // [18:7], [6:0]; early exit when the selected bin is unique.
    const int K = 3 * n_pos;
    const bool selAll = (K >= NP);
    float t = 0.0f;
    if (!selAll) {
        unsigned kk = (unsigned)K;
        // level 1
        for (int i = tid; i < 4096; i += BLKS) s_hist[i] = 0u;
        __syncthreads();
#pragma unroll
        for (int k = 0; k < NPT2; k++)
            atomicAdd(&s_hist[__float_as_uint(ce[k]) >> 19], 1u);
        __syncthreads();
        unsigned b1 = (unsigned)hist_select(s_hist, s_part, s_csuf, s_sel, kk, tid, lane, wv);
        unsigned cnt1 = s_hist[b1];
        if (cnt1 == 1u) {
#pragma unroll
            for (int k = 0; k < NPT2; k++)
                if ((__float_as_uint(ce[k]) >> 19) == b1) s_tval = ce[k];
            __syncthreads();
            t = s_tval;
        } else {
            // level 2
            __syncthreads();
            for (int i = tid; i < 4096; i += BLKS) s_hist[i] = 0u;
            __syncthreads();
#pragma unroll
            for (int k = 0; k < NPT2; k++) {
                unsigned u = __float_as_uint(ce[k]);
                if ((u >> 19) == b1) atomicAdd(&s_hist[(u >> 7) & 0xFFFu], 1u);
            }
            __syncthreads();
            unsigned b2 = (unsigned)hist_select(s_hist, s_part, s_csuf, s_sel, kk, tid, lane, wv);
            unsigned p2 = (b1 << 12) | b2;
            unsigned cnt2 = s_hist[b2];
            if (cnt2 == 1u) {
#pragma unroll
                for (int k = 0; k < NPT2; k++)
                    if ((__float_as_uint(ce[k]) >> 7) == p2) s_tval = ce[k];
                __syncthreads();
                t = s_tval;
            } else {
                // level 3
                __syncthreads();
                for (int i = tid; i < 4096; i += BLKS) s_hist[i] = 0u;
                __syncthreads();
#pragma unroll
                for (int k = 0; k < NPT2; k++) {
                    unsigned u = __float_as_uint(ce[k]);
                    if ((u >> 7) == p2) atomicAdd(&s_hist[u & 0x7Fu], 1u);
                }
                __syncthreads();
                unsigned b3 = (unsigned)hist_select(s_hist, s_part, s_csuf, s_sel, kk, tid, lane, wv);
                t = __uint_as_float((p2 << 7) | b3);
            }
        }
    }

    // sum of top-K = sum(v > t) + (K - cnt_gt) * t  (exact under ties; the
    // padded zeros never pass v > t and contribute 0 in the selAll branch)
    float sgt = 0.0f; int cgt = 0;
#pragma unroll
    for (int k = 0; k < NPT2; k++) {
        float v = ce[k];
        if (selAll || v > t) { sgt += v; cgt++; }
    }

    float a = sgt, c = conf_pos, l = loc_sum; int g = cgt;
    for (int off = 32; off; off >>= 1) {
        a += __shfl_down(a, off, 64);
        c += __shfl_down(c, off, 64);
        l += __shfl_down(l, off, 64);
        g += __shfl_down(g, off, 64);
    }
    __syncthreads();
    if (lane == 0) {
        s_fred[wv] = a; s_fred[NWAVES + wv] = c; s_fred[2 * NWAVES + wv] = l;
        s_ired[wv] = g;
    }
    __syncthreads();
    if (tid == 0) {
        float sa = 0.0f, sc = 0.0f, sl = 0.0f; int sg = 0;
#pragma unroll
        for (int w = 0; w < NWAVES; w++) {
            sa += s_fred[w]; sc += s_fred[NWAVES + w]; sl += s_fred[2 * NWAVES + w];
            sg += s_ired[w];
        }
        float conf_hn = selAll ? sa : (sa + (float)(K - sg) * t);
        conf_out[b] = sc + conf_hn;
        loc_out[b]  = sl;
        npos_out[b] = n_pos;
    }
}

// ------------------------- round-5 monolith (fallback if ws too small) -----
__global__ __launch_bounds__(BLK, 2) void mbox_row_kernel(
    const float* __restrict__ plocs, const float* __restrict__ pscores,
    const float* __restrict__ boxes, const float* __restrict__ priors,
    float* __restrict__ loc_out, float* __restrict__ conf_out,
    int* __restrict__ npos_out)
{
    const int b = blockIdx.x, tid = threadIdx.x, lane = tid & 63, wv = tid >> 6;
    const int par = tid & 1, objLo = par << 3;
    __shared__ __align__(16) float s_ce[NP];
    __shared__ unsigned char s_obj[NP];
    __shared__ float s_bcw[NO][4], s_bxy[NO][4], s_barea[NO];
    __shared__ float s_redv[NO * NWAVE]; __shared__ int s_redi[NO * NWAVE];
    __shared__ int s_bestp[NO];
    __shared__ unsigned s_hist16[16];
    __shared__ float s_tval;
    __shared__ float s_fred[3 * NWAVE]; __shared__ int s_ired[NWAVE];

    if (tid < NO * 4) ((float*)s_bcw)[tid] = boxes[(size_t)b * NO * 4 + tid];
    __syncthreads();
    if (tid < NO) {
        float cx = s_bcw[tid][0], cy = s_bcw[tid][1], w = s_bcw[tid][2], h = s_bcw[tid][3];
        s_bxy[tid][0] = cx - w * 0.5f; s_bxy[tid][1] = cy - h * 0.5f;
        s_bxy[tid][2] = cx + w * 0.5f; s_bxy[tid][3] = cy + h * 0.5f;
        s_barea[tid] = w * h;
    }
    __syncthreads();
    float rx0[8], ry0[8], rx1[8], ry1[8], ra[8];
#pragma unroll
    for (int j = 0; j < 8; j++) {
        rx0[j] = s_bxy[objLo + j][0]; ry0[j] = s_bxy[objLo + j][1];
        rx1[j] = s_bxy[objLo + j][2]; ry1[j] = s_bxy[objLo + j][3];
        ra[j]  = s_barea[objLo + j];
    }
    float tbv[8]; int tbp[8];
#pragma unroll
    for (int j = 0; j < 8; j++) { tbv[j] = -1.0f; tbp[j] = 0; }
    for (int p = (tid >> 1); p < NP; p += (BLK / 2)) {
        float4 pr = ((const float4*)priors)[p];
        float px0 = pr.x - pr.z * 0.5f, py0 = pr.y - pr.w * 0.5f;
        float px1 = pr.x + pr.z * 0.5f, py1 = pr.y + pr.w * 0.5f;
        float areab = pr.z * pr.w;
        float bv = -1.0f; int bo = objLo;
#pragma unroll
        for (int j = 0; j < 8; j++) {
            float ix0 = fmaxf(rx0[j], px0), iy0 = fmaxf(ry0[j], py0);
            float ix1 = fminf(rx1[j], px1), iy1 = fminf(ry1[j], py1);
            float iw = fmaxf(ix1 - ix0, 0.0f), ih = fmaxf(iy1 - iy0, 0.0f);
            float inter = iw * ih, den = ra[j] + areab - inter;
            float iou = inter * __builtin_amdgcn_rcpf(den);
            if (iou > bv) { bv = iou; bo = objLo + j; }
            if (iou > tbv[j]) { tbv[j] = iou; tbp[j] = p; }
        }
        float vN = __shfl_xor(bv, 1, 64); int oN = __shfl_xor(bo, 1, 64);
        bool take = par ? (vN >= bv) : (vN > bv);
        if (take) { bv = vN; bo = oN; }
        if (par == 0) s_obj[p] = (unsigned char)(bo | ((bv >= 0.5f) ? 0x80 : 0));
    }
#pragma unroll
    for (int j = 0; j < 8; j++) {
        float v = tbv[j]; int i = tbp[j];
        for (int off = 32; off >= 2; off >>= 1) {
            float v2 = __shfl_down(v, off, 64); int i2 = __shfl_down(i, off, 64);
            if (v2 > v || (v2 == v && i2 < i)) { v = v2; i = i2; }
        }
        if (lane < 2) { s_redv[(objLo + j) * NWAVE + wv] = v; s_redi[(objLo + j) * NWAVE + wv] = i; }
    }
    __syncthreads();
    if (tid < NO) {
        float v = s_redv[tid * NWAVE]; int i = s_redi[tid * NWAVE];
#pragma unroll
        for (int w = 1; w < NWAVE; w++) {
            float v2 = s_redv[tid * NWAVE + w]; int i2 = s_redi[tid * NWAVE + w];
            if (v2 > v || (v2 == v && i2 < i)) { v = v2; i = i2; }
        }
        s_bestp[tid] = i;
    }
    __syncthreads();
    if (tid == 0) {
#pragma unroll
        for (int o = 0; o < NO; o++) s_obj[s_bestp[o]] = (unsigned char)(0x80 | o);
    }
    __syncthreads();
    float loc_sum = 0.0f, conf_pos = 0.0f; int np = 0;
    const float2* sc2 = (const float2*)(pscores + (size_t)b * NP * 2);
    const float4* pl4 = (const float4*)(plocs + (size_t)b * NP * 4);
    for (int p = tid; p < NP; p += BLK) {
        unsigned m = s_obj[p]; bool pos = (m & 0x80) != 0;
        float2 s = sc2[p];
        float mx = fmaxf(s.x, s.y), dd = fabsf(s.x - s.y);
        float cev = mx + __logf(1.0f + __expf(-dd)) - (pos ? s.y : s.x);
        if (pos) {
            np++; conf_pos += cev;
            int o = m & 15;
            float4 pr = ((const float4*)priors)[p];
            float gx = (s_bcw[o][0] - pr.x) / (pr.z / 10.0f);
            float gy = (s_bcw[o][1] - pr.y) / (pr.w / 10.0f);
            float gw = __logf(s_bcw[o][2] / pr.z) * 5.0f;
            float gh = __logf(s_bcw[o][3] / pr.w) * 5.0f;
            float4 pl = pl4[p];
            loc_sum += fabsf(pl.x - gx) + fabsf(pl.y - gy) + fabsf(pl.z - gw) + fabsf(pl.w - gh);
            s_ce[p] = 0.0f;
        } else s_ce[p] = cev;
    }
    int npw = np;
    for (int off = 32; off; off >>= 1) npw += __shfl_down(npw, off, 64);
    if (lane == 0) s_ired[wv] = npw;
    __syncthreads();
    int n_pos = 0;
#pragma unroll
    for (int w = 0; w < NWAVE; w++) n_pos += s_ired[w];
    const int K = 3 * n_pos; const bool selAll = (K >= NP);
    float t = 0.0f;
    const float4* ce4 = (const float4*)s_ce;
    if (!selAll) {
        unsigned prefix = 0u, kk = (unsigned)K; bool done = false;
        for (int shift = 28; shift >= 0 && !done; shift -= 4) {
            __syncthreads();
            if (tid < 16) s_hist16[tid] = 0u;
            __syncthreads();
            unsigned maskhi = (shift == 28) ? 0u : (0xFFFFFFFFu << (shift + 4));
            for (int q = tid; q < NQ; q += BLK) {
                float4 v = ce4[q];
#pragma unroll
                for (int j = 0; j < 4; j++) {
                    unsigned u = __float_as_uint(j == 0 ? v.x : j == 1 ? v.y : j == 2 ? v.z : v.w);
                    if ((u & maskhi) == prefix) atomicAdd(&s_hist16[(u >> shift) & 15u], 1u);
                }
            }
            __syncthreads();
            int dsel = 15; unsigned cnt;
            for (;; dsel--) { cnt = s_hist16[dsel]; if (kk <= cnt || dsel == 0) break; kk -= cnt; }
            prefix |= ((unsigned)dsel << shift);
            if (shift > 0 && cnt == 1u) {
                unsigned mh = 0xFFFFFFFFu << shift;
                for (int q = tid; q < NQ; q += BLK) {
                    float4 v = ce4[q];
#pragma unroll
                    for (int j = 0; j < 4; j++) {
                        float f = (j == 0 ? v.x : j == 1 ? v.y : j == 2 ? v.z : v.w);
                        if ((__float_as_uint(f) & mh) == prefix) s_tval = f;
                    }
                }
                __syncthreads();
                t = s_tval; done = true;
            } else if (shift == 0) t = __uint_as_float(prefix);
        }
    }
    float sgt = 0.0f; int cgt = 0;
    for (int q = tid; q < NQ; q += BLK) {
        float4 v = ce4[q];
        if (selAll || v.x > t) { sgt += v.x; cgt++; }
        if (selAll || v.y > t) { sgt += v.y; cgt++; }
        if (selAll || v.z > t) { sgt += v.z; cgt++; }
        if (selAll || v.w > t) { sgt += v.w; cgt++; }
    }
    float a = sgt, c = conf_pos, l = loc_sum; int g = cgt;
    for (int off = 32; off; off >>= 1) {
        a += __shfl_down(a, off, 64); c += __shfl_down(c, off, 64);
        l += __shfl_down(l, off, 64); g += __shfl_down(g, off, 64);
    }
    __syncthreads();
    if (lane == 0) { s_fred[wv] = a; s_fred[NWAVE + wv] = c; s_fred[2 * NWAVE + wv] = l; s_ired[wv] = g; }
    __syncthreads();
    if (tid == 0) {
        float sa = 0, sc = 0, sl = 0; int sg = 0;
#pragma unroll
        for (int w = 0; w < NWAVE; w++) { sa += s_fred[w]; sc += s_fred[NWAVE + w]; sl += s_fred[2 * NWAVE + w]; sg += s_ired[w]; }
        float conf_hn = selAll ? sa : (sa + (float)(K - sg) * t);
        conf_out[b] = sc + conf_hn; loc_out[b] = sl; npos_out[b] = n_pos;
    }
}

__global__ __launch_bounds__(256) void mbox_finalize_kernel(
    const float* __restrict__ loc_in, const float* __restrict__ conf_in,
    const int* __restrict__ npos_in, int B, float* __restrict__ out)
{
    __shared__ float sl[4], sc[4];
    __shared__ int si[4];
    int tid = threadIdx.x, lane = tid & 63, wv = tid >> 6;
    float l = 0.0f, c = 0.0f; int n = 0;
    for (int i = tid; i < B; i += 256) { l += loc_in[i]; c += conf_in[i]; n += npos_in[i]; }
    for (int off = 32; off; off >>= 1) {
        l += __shfl_down(l, off, 64);
        c += __shfl_down(c, off, 64);
        n += __shfl_down(n, off, 64);
    }
    if (lane == 0) { sl[wv] = l; sc[wv] = c; si[wv] = n; }
    __syncthreads();
    if (tid == 0) {
        float tl = sl[0] + sl[1] + sl[2] + sl[3];
        float tc = sc[0] + sc[1] + sc[2] + sc[3];
        int tn = si[0] + si[1] + si[2] + si[3];
        float fn = (float)tn;
        out[0] = tc / fn + tl / (fn * 4.0f);
    }
}

extern "C" void kernel_launch(void* const* d_in, const int* in_sizes, int n_in,
                              void* d_out, int out_size, void* d_ws, size_t ws_size,
                              hipStream_t stream) {
    const float* plocs   = (const float*)d_in[0];
    const float* pscores = (const float*)d_in[1];
    const float* boxes   = (const float*)d_in[2];
    const float* priors  = (const float*)d_in[3];
    const int B = in_sizes[0] / (NP * 4);

    // workspace layout (back to the compact R0 shape: no ce_g)
    float* loc_ws  = (float*)d_ws;                                 // B
    float* conf_ws = loc_ws + B;                                   // B
    int*   np_ws   = (int*)(conf_ws + B);                          // B
    float* g_bv    = (float*)(np_ws + B);                          // B*NO*SPLIT
    int*   g_bi    = (int*)(g_bv + (size_t)B * NO * SPLIT);        // B*NO*SPLIT
    unsigned char* g_obj = (unsigned char*)(g_bi + (size_t)B * NO * SPLIT);
    size_t need = (size_t)(3 * B) * 4 + (size_t)B * NO * SPLIT * 8 + (size_t)B * NP;

    if (ws_size >= need) {
        match_kernel<<<dim3(B, SPLIT), BLK, 0, stream>>>(boxes, priors, g_obj, g_bv, g_bi);
        loss2_kernel<<<B, BLKS, 0, stream>>>(plocs, pscores, boxes, priors,
                                             g_obj, g_bv, g_bi,
                                             loc_ws, conf_ws, np_ws);
    } else {
        mbox_row_kernel<<<B, BLK, 0, stream>>>(plocs, pscores, boxes, priors,
                                               loc_ws, conf_ws, np_ws);
    }
    mbox_finalize_kernel<<<1, 256, 0, stream>>>(loc_ws, conf_ws, np_ws, B, (float*)d_out);
}

// Round 11
// 177.115 us; speedup vs baseline: 1.1385x; 1.0072x over previous
//
#include <hip/hip_runtime.h>

#define NP 8732
#define NO 16
#define BLKS 1024            // fused kernel block size (16 waves)
#define NWAVES (BLKS / 64)
#define NPT2 9               // ceil(NP / 1024) priors per thread

// ---------------------------------------------------------------------------
// Evidence log:
//  - Match body (solo-thread priors + SGPR corners, predicated `if(ov)`):
//    47.5us standalone, VGPR 36. Ballot wave-skip REGRESSED; pf[] prefetch
//    and no-ov-guard both SPILL (WRITE_SIZE is the tripwire). The exec-mask
//    `if (ov)` form is the regalloc-stable form -- carried verbatim.
//  - R14: residual (total - match) ~146us, invariant across monolith/split.
//  - R17: cross-container clock noise ~17% -- check hbm_gbps (116 = normal,
//    96 = slow container) before believing any delta.
//  - R18 (ce+select fused at BLK=1024): 193.1 -> 178.4us on normal-clock
//    container. loss2 < 47us (below match in top-5). Kernel sum ~96us =>
//    ~80us is launch/drain/gap overhead. Fusion works; repeat it.
//  - R19: FULL fusion, grid B x 1024: per-block match (9 priors/thread,
//    same total waves as SPLIT=4) + block-local argmax (min-index-argmax
//    is associative => any reduction shape exact) + in-LDS forced
//    overwrite + loss2 body. Deletes match launch + drain + 9MB g_obj
//    roundtrip + g_bv/g_bi. LDS 59.5KB < 64KB; VGPR cap 64 (lb 1024,8).
// ---------------------------------------------------------------------------

__device__ __forceinline__ float rfl(float x) {
    return __uint_as_float(__builtin_amdgcn_readfirstlane(__float_as_uint(x)));
}

// Histogram bin selection over 4096 bins (256-thread scan structure; threads
// >= 256 participate only in barriers). Finds bin holding the kk-th largest;
// updates kk to the rank within the bin.
__device__ __forceinline__ int hist_select(unsigned* hist, unsigned* s_part,
                                           unsigned* s_csuf, unsigned* s_sel,
                                           unsigned& kk, int tid, int lane, int wv)
{
    if (tid < 256) {
        unsigned ps = 0;
#pragma unroll
        for (int i = 0; i < 16; i++) ps += hist[tid * 16 + i];
        s_part[tid] = ps;
    }
    __syncthreads();
    if (wv == 0) {
        unsigned c0 = s_part[4 * lane + 0], c1 = s_part[4 * lane + 1];
        unsigned c2 = s_part[4 * lane + 2], c3 = s_part[4 * lane + 3];
        unsigned g = c0 + c1 + c2 + c3;
        unsigned incl = g;
#pragma unroll
        for (int off = 1; off < 64; off <<= 1) {
            unsigned o = __shfl_down(incl, off, 64);
            if (lane + off < 64) incl += o;
        }
        unsigned excl = incl - g;           // count in chunks above this one
        s_csuf[4 * lane + 3] = excl;
        s_csuf[4 * lane + 2] = excl + c3;
        s_csuf[4 * lane + 1] = excl + c3 + c2;
        s_csuf[4 * lane + 0] = excl + c3 + c2 + c1;
    }
    __syncthreads();
    if (tid < 256) {
        unsigned base = s_csuf[tid];        // count in bins >= 16*(tid+1)
        if (base < kk && kk <= base + s_part[tid]) {   // exactly one thread
            unsigned run = base;
            for (int i = 15; i >= 0; i--) {
                unsigned h = hist[tid * 16 + i];
                if (kk <= run + h) { s_sel[0] = (unsigned)(tid * 16 + i); s_sel[1] = kk - run; break; }
                run += h;
            }
        }
    }
    __syncthreads();
    kk = s_sel[1];
    return (int)s_sel[0];
}

// Fused kernel: one block per row. Phase 1: match all NP priors vs 16
// objects (9 priors/thread), block-local per-object argmax, forced-prior
// overwrite in LDS. Phase 2: CE + loc + npos + 4096-bin top-K select.
__global__ __launch_bounds__(BLKS, 8) void fused_kernel(
    const float* __restrict__ plocs,    // [B,P,4]
    const float* __restrict__ pscores,  // [B,P,2]
    const float* __restrict__ boxes,    // [B,O,4] cxcy
    const float* __restrict__ priors,   // [P,4]  cxcy
    float* __restrict__ loc_out,        // [B]
    float* __restrict__ conf_out,       // [B]
    int*   __restrict__ npos_out)       // [B]
{
    const int b    = blockIdx.x;
    const int tid  = threadIdx.x;
    const int lane = tid & 63;
    const int wv   = tid >> 6;

    __shared__ unsigned char s_obj[NP];
    __shared__ unsigned s_hist[4096];
    __shared__ float s_pv[NWAVES][NO][16];
    __shared__ int   s_pi[NWAVES][NO][16];
    __shared__ unsigned s_part[256];
    __shared__ unsigned s_csuf[256];
    __shared__ unsigned s_sel[2];
    __shared__ float s_bcw[NO][4];
    __shared__ int   s_bestp[NO];
    __shared__ float s_tval;
    __shared__ float s_fred[3 * NWAVES];
    __shared__ int   s_ired[NWAVES];

    // boxes for the CE phase (raw cxcywh)
    if (tid < NO * 4) ((float*)s_bcw)[tid] = boxes[(size_t)b * NO * 4 + tid];

    // ---- Phase 1: match -------------------------------------------------
    // wave-uniform object corners -> SGPRs via readfirstlane
    float sx0[NO], sy0[NO], sx1[NO], sy1[NO], ra[NO];
    {
        const float4* bx4 = (const float4*)(boxes + (size_t)b * NO * 4);
#pragma unroll
        for (int j = 0; j < NO; j++) {
            float4 o = bx4[j];
            float hx = o.z * 0.5f, hy = o.w * 0.5f;
            sx0[j] = rfl(o.x - hx); sy0[j] = rfl(o.y - hy);
            sx1[j] = rfl(o.x + hx); sy1[j] = rfl(o.y + hy);
            ra[j]  = o.z * o.w;
        }
    }

    float tbv[NO]; int tbp[NO];
#pragma unroll
    for (int j = 0; j < NO; j++) { tbv[j] = -1.0f; tbp[j] = 0; }

    for (int k = 0; k < NPT2; k++) {
        int p0 = tid + k * BLKS;
        bool valid = p0 < NP;
        int p = valid ? p0 : NP - 1;          // clamped duplicate: harmless,
                                              // (v,i) identical under tie rule
        float4 pr = ((const float4*)priors)[p];
        float px0 = pr.x - pr.z * 0.5f, py0 = pr.y - pr.w * 0.5f;
        float px1 = pr.x + pr.z * 0.5f, py1 = pr.y + pr.w * 0.5f;
        float areab = pr.z * pr.w;
        if (!valid) px0 = 4.0f;               // object corners <= ~1.3: every
                                              // overlap test fails for this lane
        float bv = -1.0f; int bo = 0;
#pragma unroll
        for (int j = 0; j < NO; j++) {
            bool ov = (sx1[j] >= px0) && (px1 >= sx0[j]) &&
                      (sy1[j] >= py0) && (py1 >= sy0[j]);
            if (ov) {   // exec-masked body; non-overlap pairs have iou==0
                float ix0 = fmaxf(sx0[j], px0);
                float iy0 = fmaxf(sy0[j], py0);
                float ix1 = fminf(sx1[j], px1);
                float iy1 = fminf(sy1[j], py1);
                float iw = fmaxf(ix1 - ix0, 0.0f);
                float ih = fmaxf(iy1 - iy0, 0.0f);
                float inter = iw * ih;
                float den = ra[j] + areab - inter;
                float iou = inter * __builtin_amdgcn_rcpf(den);
                if (iou > bv)     { bv = iou; bo = j; }        // first-wins over j
                if (iou > tbv[j]) { tbv[j] = iou; tbp[j] = p; } // min-index over p
            }
        }
        if (valid) s_obj[p] = (unsigned char)(bo | ((bv >= 0.5f) ? 0x80 : 0));
    }

    // per-object block argmax: 2 shfl rounds -> 16 partials/wave -> LDS
#pragma unroll
    for (int j = 0; j < NO; j++) {
        float v = tbv[j]; int i = tbp[j];
        float v2 = __shfl_down(v, 32, 64); int i2 = __shfl_down(i, 32, 64);
        if (v2 > v || (v2 == v && i2 < i)) { v = v2; i = i2; }
        v2 = __shfl_down(v, 16, 64); i2 = __shfl_down(i, 16, 64);
        if (v2 > v || (v2 == v && i2 < i)) { v = v2; i = i2; }
        if (lane < 16) { s_pv[wv][j][lane] = v; s_pi[wv][j][lane] = i; }
    }
    __syncthreads();
    if (tid < 256) {   // 16 threads per object fold 16 waves x 16 partials
        const int j = tid >> 4, e = tid & 15;
        float v = s_pv[0][j][e]; int i = s_pi[0][j][e];
#pragma unroll
        for (int w = 1; w < NWAVES; w++) {
            float v2 = s_pv[w][j][e]; int i2 = s_pi[w][j][e];
            if (v2 > v || (v2 == v && i2 < i)) { v = v2; i = i2; }
        }
#pragma unroll
        for (int off = 8; off >= 1; off >>= 1) {
            float v2 = __shfl_down(v, off, 16); int i2 = __shfl_down(i, off, 16);
            if (v2 > v || (v2 == v && i2 < i)) { v = v2; i = i2; }
        }
        if (e == 0) s_bestp[j] = i;
    }
    __syncthreads();
    if (tid == 0) {   // serial ascending: last o wins on duplicate priors
#pragma unroll
        for (int o = 0; o < NO; o++) s_obj[s_bestp[o]] = (unsigned char)(0x80 | o);
    }
    __syncthreads();

    // ---- Phase 2: CE + loc + top-K select -------------------------------
    float ce[NPT2];
    float loc_sum = 0.0f, conf_pos = 0.0f; int np = 0;
    const float2* sc2 = (const float2*)(pscores + (size_t)b * NP * 2);
    const float4* pl4 = (const float4*)(plocs  + (size_t)b * NP * 4);
#pragma unroll
    for (int k = 0; k < NPT2; k++) {
        int p = tid + k * BLKS;
        float v = 0.0f;
        if (p < NP) {
            unsigned m = s_obj[p];
            bool pos = (m & 0x80) != 0;
            float2 s = sc2[p];
            float mx = fmaxf(s.x, s.y);
            float dd = fabsf(s.x - s.y);
            float cev = mx + __logf(1.0f + __expf(-dd)) - (pos ? s.y : s.x);
            if (pos) {
                np++;
                conf_pos += cev;
                int o = m & 15;
                float4 pr = ((const float4*)priors)[p];
                float gx = (s_bcw[o][0] - pr.x) / (pr.z / 10.0f);
                float gy = (s_bcw[o][1] - pr.y) / (pr.w / 10.0f);
                float gw = __logf(s_bcw[o][2] / pr.z) * 5.0f;
                float gh = __logf(s_bcw[o][3] / pr.w) * 5.0f;
                float4 pl = pl4[p];
                loc_sum += fabsf(pl.x - gx) + fabsf(pl.y - gy)
                         + fabsf(pl.z - gw) + fabsf(pl.w - gh);
            } else {
                v = cev;
            }
        }
        ce[k] = v;
    }

    int npw = np;
    for (int off = 32; off; off >>= 1) npw += __shfl_down(npw, off, 64);
    if (lane == 0) s_ired[wv] = npw;
    __syncthreads();
    int n_pos = 0;
#pragma unroll
    for (int w = 0; w < NWAVES; w++) n_pos += s_ired[w];

    // select K-th largest CE: up to 3 histogram levels over bits [30:19],
    // [18:7], [6:0]; early exit when the selected bin is unique.
    const int K = 3 * n_pos;
    const bool selAll = (K >= NP);
    float t = 0.0f;
    if (!selAll) {
        unsigned kk = (unsigned)K;
        // level 1
        for (int i = tid; i < 4096; i += BLKS) s_hist[i] = 0u;
        __syncthreads();
#pragma unroll
        for (int k = 0; k < NPT2; k++)
            atomicAdd(&s_hist[__float_as_uint(ce[k]) >> 19], 1u);
        __syncthreads();
        unsigned b1 = (unsigned)hist_select(s_hist, s_part, s_csuf, s_sel, kk, tid, lane, wv);
        unsigned cnt1 = s_hist[b1];
        if (cnt1 == 1u) {
#pragma unroll
            for (int k = 0; k < NPT2; k++)
                if ((__float_as_uint(ce[k]) >> 19) == b1) s_tval = ce[k];
            __syncthreads();
            t = s_tval;
        } else {
            // level 2
            __syncthreads();
            for (int i = tid; i < 4096; i += BLKS) s_hist[i] = 0u;
            __syncthreads();
#pragma unroll
            for (int k = 0; k < NPT2; k++) {
                unsigned u = __float_as_uint(ce[k]);
                if ((u >> 19) == b1) atomicAdd(&s_hist[(u >> 7) & 0xFFFu], 1u);
            }
            __syncthreads();
            unsigned b2 = (unsigned)hist_select(s_hist, s_part, s_csuf, s_sel, kk, tid, lane, wv);
            unsigned p2 = (b1 << 12) | b2;
            unsigned cnt2 = s_hist[b2];
            if (cnt2 == 1u) {
#pragma unroll
                for (int k = 0; k < NPT2; k++)
                    if ((__float_as_uint(ce[k]) >> 7) == p2) s_tval = ce[k];
                __syncthreads();
                t = s_tval;
            } else {
                // level 3
                __syncthreads();
                for (int i = tid; i < 4096; i += BLKS) s_hist[i] = 0u;
                __syncthreads();
#pragma unroll
                for (int k = 0; k < NPT2; k++) {
                    unsigned u = __float_as_uint(ce[k]);
                    if ((u >> 7) == p2) atomicAdd(&s_hist[u & 0x7Fu], 1u);
                }
                __syncthreads();
                unsigned b3 = (unsigned)hist_select(s_hist, s_part, s_csuf, s_sel, kk, tid, lane, wv);
                t = __uint_as_float((p2 << 7) | b3);
            }
        }
    }

    // sum of top-K = sum(v > t) + (K - cnt_gt) * t  (exact under ties; the
    // padded zeros never pass v > t and contribute 0 in the selAll branch)
    float sgt = 0.0f; int cgt = 0;
#pragma unroll
    for (int k = 0; k < NPT2; k++) {
        float v = ce[k];
        if (selAll || v > t) { sgt += v; cgt++; }
    }

    float a = sgt, c = conf_pos, l = loc_sum; int g = cgt;
    for (int off = 32; off; off >>= 1) {
        a += __shfl_down(a, off, 64);
        c += __shfl_down(c, off, 64);
        l += __shfl_down(l, off, 64);
        g += __shfl_down(g, off, 64);
    }
    __syncthreads();
    if (lane == 0) {
        s_fred[wv] = a; s_fred[NWAVES + wv] = c; s_fred[2 * NWAVES + wv] = l;
        s_ired[wv] = g;
    }
    __syncthreads();
    if (tid == 0) {
        float sa = 0.0f, sc = 0.0f, sl = 0.0f; int sg = 0;
#pragma unroll
        for (int w = 0; w < NWAVES; w++) {
            sa += s_fred[w]; sc += s_fred[NWAVES + w]; sl += s_fred[2 * NWAVES + w];
            sg += s_ired[w];
        }
        float conf_hn = selAll ? sa : (sa + (float)(K - sg) * t);
        conf_out[b] = sc + conf_hn;
        loc_out[b]  = sl;
        npos_out[b] = n_pos;
    }
}

__global__ __launch_bounds__(256) void mbox_finalize_kernel(
    const float* __restrict__ loc_in, const float* __restrict__ conf_in,
    const int* __restrict__ npos_in, int B, float* __restrict__ out)
{
    __shared__ float sl[4], sc[4];
    __shared__ int si[4];
    int tid = threadIdx.x, lane = tid & 63, wv = tid >> 6;
    float l = 0.0f, c = 0.0f; int n = 0;
    for (int i = tid; i < B; i += 256) { l += loc_in[i]; c += conf_in[i]; n += npos_in[i]; }
    for (int off = 32; off; off >>= 1) {
        l += __shfl_down(l, off, 64);
        c += __shfl_down(c, off, 64);
        n += __shfl_down(n, off, 64);
    }
    if (lane == 0) { sl[wv] = l; sc[wv] = c; si[wv] = n; }
    __syncthreads();
    if (tid == 0) {
        float tl = sl[0] + sl[1] + sl[2] + sl[3];
        float tc = sc[0] + sc[1] + sc[2] + sc[3];
        int tn = si[0] + si[1] + si[2] + si[3];
        float fn = (float)tn;
        out[0] = tc / fn + tl / (fn * 4.0f);
    }
}

extern "C" void kernel_launch(void* const* d_in, const int* in_sizes, int n_in,
                              void* d_out, int out_size, void* d_ws, size_t ws_size,
                              hipStream_t stream) {
    const float* plocs   = (const float*)d_in[0];
    const float* pscores = (const float*)d_in[1];
    const float* boxes   = (const float*)d_in[2];
    const float* priors  = (const float*)d_in[3];
    const int B = in_sizes[0] / (NP * 4);

    float* loc_ws  = (float*)d_ws;     // B
    float* conf_ws = loc_ws + B;       // B
    int*   np_ws   = (int*)(conf_ws + B);

    fused_kernel<<<B, BLKS, 0, stream>>>(plocs, pscores, boxes, priors,
                                         loc_ws, conf_ws, np_ws);
    mbox_finalize_kernel<<<1, 256, 0, stream>>>(loc_ws, conf_ws, np_ws, B, (float*)d_out);
}

// Round 12
// 176.649 us; speedup vs baseline: 1.1415x; 1.0026x over previous
//
#include <hip/hip_runtime.h>

#define NP 8732
#define NO 16
#define BLKS 1024            // fused kernel block size (16 waves)
#define NWAVES (BLKS / 64)
#define NPT2 9               // ceil(NP / 1024) priors per thread

// ---------------------------------------------------------------------------
// Evidence log:
//  - Match body: predicated guard form is regalloc-stable (no-guard and
//    pf[] prefetch both SPILL -- WRITE_SIZE is the tripwire). Ballot
//    wave-skip regressed. Two stable guard forms measured at 256 thr:
//    R1 shared-test (test=fminf(iw,ih)>0, body reuses iw*ih, ~19 inst)
//    47.9us; R5 corner-test + clamped recompute (~26 inst) 47.5us -- tied
//    when latency-bound at 16 waves/CU.
//  - R17: cross-container clock noise ~17% -- check hbm_gbps (116 normal).
//  - R18 (ce+select fusion): 193->178.4. R19 (full fusion, grid B x1024):
//    fused_kernel 77us, total 177.1. Overhead budget now pinned: kernels
//    81us, ~96us fixed harness window (launch removal worth only ~1.3us).
//    fused counters: VALUBusy 53.8, occ 78%, HBM 6%, conflicts 841K
//    (~1.4us -- negligible). Issue-bound => instruction count now pays.
//  - R20: switch fused match loop to the R1 shared-test form (-27% match
//    issue). Watch VGPR/WRITE_SIZE for spill (revert if WRITE >= 50MB).
// ---------------------------------------------------------------------------

__device__ __forceinline__ float rfl(float x) {
    return __uint_as_float(__builtin_amdgcn_readfirstlane(__float_as_uint(x)));
}

// Histogram bin selection over 4096 bins (256-thread scan structure; threads
// >= 256 participate only in barriers). Finds bin holding the kk-th largest;
// updates kk to the rank within the bin.
__device__ __forceinline__ int hist_select(unsigned* hist, unsigned* s_part,
                                           unsigned* s_csuf, unsigned* s_sel,
                                           unsigned& kk, int tid, int lane, int wv)
{
    if (tid < 256) {
        unsigned ps = 0;
#pragma unroll
        for (int i = 0; i < 16; i++) ps += hist[tid * 16 + i];
        s_part[tid] = ps;
    }
    __syncthreads();
    if (wv == 0) {
        unsigned c0 = s_part[4 * lane + 0], c1 = s_part[4 * lane + 1];
        unsigned c2 = s_part[4 * lane + 2], c3 = s_part[4 * lane + 3];
        unsigned g = c0 + c1 + c2 + c3;
        unsigned incl = g;
#pragma unroll
        for (int off = 1; off < 64; off <<= 1) {
            unsigned o = __shfl_down(incl, off, 64);
            if (lane + off < 64) incl += o;
        }
        unsigned excl = incl - g;           // count in chunks above this one
        s_csuf[4 * lane + 3] = excl;
        s_csuf[4 * lane + 2] = excl + c3;
        s_csuf[4 * lane + 1] = excl + c3 + c2;
        s_csuf[4 * lane + 0] = excl + c3 + c2 + c1;
    }
    __syncthreads();
    if (tid < 256) {
        unsigned base = s_csuf[tid];        // count in bins >= 16*(tid+1)
        if (base < kk && kk <= base + s_part[tid]) {   // exactly one thread
            unsigned run = base;
            for (int i = 15; i >= 0; i--) {
                unsigned h = hist[tid * 16 + i];
                if (kk <= run + h) { s_sel[0] = (unsigned)(tid * 16 + i); s_sel[1] = kk - run; break; }
                run += h;
            }
        }
    }
    __syncthreads();
    kk = s_sel[1];
    return (int)s_sel[0];
}

// Fused kernel: one block per row. Phase 1: match all NP priors vs 16
// objects (9 priors/thread), block-local per-object argmax, forced-prior
// overwrite in LDS. Phase 2: CE + loc + npos + 4096-bin top-K select.
__global__ __launch_bounds__(BLKS, 8) void fused_kernel(
    const float* __restrict__ plocs,    // [B,P,4]
    const float* __restrict__ pscores,  // [B,P,2]
    const float* __restrict__ boxes,    // [B,O,4] cxcy
    const float* __restrict__ priors,   // [P,4]  cxcy
    float* __restrict__ loc_out,        // [B]
    float* __restrict__ conf_out,       // [B]
    int*   __restrict__ npos_out)       // [B]
{
    const int b    = blockIdx.x;
    const int tid  = threadIdx.x;
    const int lane = tid & 63;
    const int wv   = tid >> 6;

    __shared__ unsigned char s_obj[NP];
    __shared__ unsigned s_hist[4096];
    __shared__ float s_pv[NWAVES][NO][16];
    __shared__ int   s_pi[NWAVES][NO][16];
    __shared__ unsigned s_part[256];
    __shared__ unsigned s_csuf[256];
    __shared__ unsigned s_sel[2];
    __shared__ float s_bcw[NO][4];
    __shared__ int   s_bestp[NO];
    __shared__ float s_tval;
    __shared__ float s_fred[3 * NWAVES];
    __shared__ int   s_ired[NWAVES];

    // boxes for the CE phase (raw cxcywh)
    if (tid < NO * 4) ((float*)s_bcw)[tid] = boxes[(size_t)b * NO * 4 + tid];

    // ---- Phase 1: match -------------------------------------------------
    // wave-uniform object corners -> SGPRs via readfirstlane
    float sx0[NO], sy0[NO], sx1[NO], sy1[NO], ra[NO];
    {
        const float4* bx4 = (const float4*)(boxes + (size_t)b * NO * 4);
#pragma unroll
        for (int j = 0; j < NO; j++) {
            float4 o = bx4[j];
            float hx = o.z * 0.5f, hy = o.w * 0.5f;
            sx0[j] = rfl(o.x - hx); sy0[j] = rfl(o.y - hy);
            sx1[j] = rfl(o.x + hx); sy1[j] = rfl(o.y + hy);
            ra[j]  = o.z * o.w;
        }
    }

    float tbv[NO]; int tbp[NO];
#pragma unroll
    for (int j = 0; j < NO; j++) { tbv[j] = -1.0f; tbp[j] = 0; }

    for (int k = 0; k < NPT2; k++) {
        int p0 = tid + k * BLKS;
        bool valid = p0 < NP;
        int p = valid ? p0 : NP - 1;          // clamped duplicate: harmless,
                                              // (v,i) identical under tie rule
        float4 pr = ((const float4*)priors)[p];
        float px0 = pr.x - pr.z * 0.5f, py0 = pr.y - pr.w * 0.5f;
        float px1 = pr.x + pr.z * 0.5f, py1 = pr.y + pr.w * 0.5f;
        float areab = pr.z * pr.w;
        if (!valid) px0 = 4.0f;               // object corners <= ~1.3: every
                                              // overlap test fails for this lane
        float bv = -1.0f; int bo = 0;
#pragma unroll
        for (int j = 0; j < NO; j++) {
            // R1 shared-test form: test and body share the max/min results
            float ix0 = fmaxf(sx0[j], px0);
            float iy0 = fmaxf(sy0[j], py0);
            float ix1 = fminf(sx1[j], px1);
            float iy1 = fminf(sy1[j], py1);
            float iw = ix1 - ix0;
            float ih = iy1 - iy0;
            bool ov = fminf(iw, ih) > 0.0f;
            if (ov) {   // exec-masked body; active lanes have iw,ih > 0
                float inter = iw * ih;
                float den = ra[j] + areab - inter;
                float iou = inter * __builtin_amdgcn_rcpf(den);
                if (iou > bv)     { bv = iou; bo = j; }        // first-wins over j
                if (iou > tbv[j]) { tbv[j] = iou; tbp[j] = p; } // min-index over p
            }
        }
        if (valid) s_obj[p] = (unsigned char)(bo | ((bv >= 0.5f) ? 0x80 : 0));
    }

    // per-object block argmax: 2 shfl rounds -> 16 partials/wave -> LDS
#pragma unroll
    for (int j = 0; j < NO; j++) {
        float v = tbv[j]; int i = tbp[j];
        float v2 = __shfl_down(v, 32, 64); int i2 = __shfl_down(i, 32, 64);
        if (v2 > v || (v2 == v && i2 < i)) { v = v2; i = i2; }
        v2 = __shfl_down(v, 16, 64); i2 = __shfl_down(i, 16, 64);
        if (v2 > v || (v2 == v && i2 < i)) { v = v2; i = i2; }
        if (lane < 16) { s_pv[wv][j][lane] = v; s_pi[wv][j][lane] = i; }
    }
    __syncthreads();
    if (tid < 256) {   // 16 threads per object fold 16 waves x 16 partials
        const int j = tid >> 4, e = tid & 15;
        float v = s_pv[0][j][e]; int i = s_pi[0][j][e];
#pragma unroll
        for (int w = 1; w < NWAVES; w++) {
            float v2 = s_pv[w][j][e]; int i2 = s_pi[w][j][e];
            if (v2 > v || (v2 == v && i2 < i)) { v = v2; i = i2; }
        }
#pragma unroll
        for (int off = 8; off >= 1; off >>= 1) {
            float v2 = __shfl_down(v, off, 16); int i2 = __shfl_down(i, off, 16);
            if (v2 > v || (v2 == v && i2 < i)) { v = v2; i = i2; }
        }
        if (e == 0) s_bestp[j] = i;
    }
    __syncthreads();
    if (tid == 0) {   // serial ascending: last o wins on duplicate priors
#pragma unroll
        for (int o = 0; o < NO; o++) s_obj[s_bestp[o]] = (unsigned char)(0x80 | o);
    }
    __syncthreads();

    // ---- Phase 2: CE + loc + top-K select -------------------------------
    float ce[NPT2];
    float loc_sum = 0.0f, conf_pos = 0.0f; int np = 0;
    const float2* sc2 = (const float2*)(pscores + (size_t)b * NP * 2);
    const float4* pl4 = (const float4*)(plocs  + (size_t)b * NP * 4);
#pragma unroll
    for (int k = 0; k < NPT2; k++) {
        int p = tid + k * BLKS;
        float v = 0.0f;
        if (p < NP) {
            unsigned m = s_obj[p];
            bool pos = (m & 0x80) != 0;
            float2 s = sc2[p];
            float mx = fmaxf(s.x, s.y);
            float dd = fabsf(s.x - s.y);
            float cev = mx + __logf(1.0f + __expf(-dd)) - (pos ? s.y : s.x);
            if (pos) {
                np++;
                conf_pos += cev;
                int o = m & 15;
                float4 pr = ((const float4*)priors)[p];
                float gx = (s_bcw[o][0] - pr.x) / (pr.z / 10.0f);
                float gy = (s_bcw[o][1] - pr.y) / (pr.w / 10.0f);
                float gw = __logf(s_bcw[o][2] / pr.z) * 5.0f;
                float gh = __logf(s_bcw[o][3] / pr.w) * 5.0f;
                float4 pl = pl4[p];
                loc_sum += fabsf(pl.x - gx) + fabsf(pl.y - gy)
                         + fabsf(pl.z - gw) + fabsf(pl.w - gh);
            } else {
                v = cev;
            }
        }
        ce[k] = v;
    }

    int npw = np;
    for (int off = 32; off; off >>= 1) npw += __shfl_down(npw, off, 64);
    if (lane == 0) s_ired[wv] = npw;
    __syncthreads();
    int n_pos = 0;
#pragma unroll
    for (int w = 0; w < NWAVES; w++) n_pos += s_ired[w];

    // select K-th largest CE: up to 3 histogram levels over bits [30:19],
    // [18:7], [6:0]; early exit when the selected bin is unique.
    const int K = 3 * n_pos;
    const bool selAll = (K >= NP);
    float t = 0.0f;
    if (!selAll) {
        unsigned kk = (unsigned)K;
        // level 1
        for (int i = tid; i < 4096; i += BLKS) s_hist[i] = 0u;
        __syncthreads();
#pragma unroll
        for (int k = 0; k < NPT2; k++)
            atomicAdd(&s_hist[__float_as_uint(ce[k]) >> 19], 1u);
        __syncthreads();
        unsigned b1 = (unsigned)hist_select(s_hist, s_part, s_csuf, s_sel, kk, tid, lane, wv);
        unsigned cnt1 = s_hist[b1];
        if (cnt1 == 1u) {
#pragma unroll
            for (int k = 0; k < NPT2; k++)
                if ((__float_as_uint(ce[k]) >> 19) == b1) s_tval = ce[k];
            __syncthreads();
            t = s_tval;
        } else {
            // level 2
            __syncthreads();
            for (int i = tid; i < 4096; i += BLKS) s_hist[i] = 0u;
            __syncthreads();
#pragma unroll
            for (int k = 0; k < NPT2; k++) {
                unsigned u = __float_as_uint(ce[k]);
                if ((u >> 19) == b1) atomicAdd(&s_hist[(u >> 7) & 0xFFFu], 1u);
            }
            __syncthreads();
            unsigned b2 = (unsigned)hist_select(s_hist, s_part, s_csuf, s_sel, kk, tid, lane, wv);
            unsigned p2 = (b1 << 12) | b2;
            unsigned cnt2 = s_hist[b2];
            if (cnt2 == 1u) {
#pragma unroll
                for (int k = 0; k < NPT2; k++)
                    if ((__float_as_uint(ce[k]) >> 7) == p2) s_tval = ce[k];
                __syncthreads();
                t = s_tval;
            } else {
                // level 3
                __syncthreads();
                for (int i = tid; i < 4096; i += BLKS) s_hist[i] = 0u;
                __syncthreads();
#pragma unroll
                for (int k = 0; k < NPT2; k++) {
                    unsigned u = __float_as_uint(ce[k]);
                    if ((u >> 7) == p2) atomicAdd(&s_hist[u & 0x7Fu], 1u);
                }
                __syncthreads();
                unsigned b3 = (unsigned)hist_select(s_hist, s_part, s_csuf, s_sel, kk, tid, lane, wv);
                t = __uint_as_float((p2 << 7) | b3);
            }
        }
    }

    // sum of top-K = sum(v > t) + (K - cnt_gt) * t  (exact under ties; the
    // padded zeros never pass v > t and contribute 0 in the selAll branch)
    float sgt = 0.0f; int cgt = 0;
#pragma unroll
    for (int k = 0; k < NPT2; k++) {
        float v = ce[k];
        if (selAll || v > t) { sgt += v; cgt++; }
    }

    float a = sgt, c = conf_pos, l = loc_sum; int g = cgt;
    for (int off = 32; off; off >>= 1) {
        a += __shfl_down(a, off, 64);
        c += __shfl_down(c, off, 64);
        l += __shfl_down(l, off, 64);
        g += __shfl_down(g, off, 64);
    }
    __syncthreads();
    if (lane == 0) {
        s_fred[wv] = a; s_fred[NWAVES + wv] = c; s_fred[2 * NWAVES + wv] = l;
        s_ired[wv] = g;
    }
    __syncthreads();
    if (tid == 0) {
        float sa = 0.0f, sc = 0.0f, sl = 0.0f; int sg = 0;
#pragma unroll
        for (int w = 0; w < NWAVES; w++) {
            sa += s_fred[w]; sc += s_fred[NWAVES + w]; sl += s_fred[2 * NWAVES + w];
            sg += s_ired[w];
        }
        float conf_hn = selAll ? sa : (sa + (float)(K - sg) * t);
        conf_out[b] = sc + conf_hn;
        loc_out[b]  = sl;
        npos_out[b] = n_pos;
    }
}

__global__ __launch_bounds__(256) void mbox_finalize_kernel(
    const float* __restrict__ loc_in, const float* __restrict__ conf_in,
    const int* __restrict__ npos_in, int B, float* __restrict__ out)
{
    __shared__ float sl[4], sc[4];
    __shared__ int si[4];
    int tid = threadIdx.x, lane = tid & 63, wv = tid >> 6;
    float l = 0.0f, c = 0.0f; int n = 0;
    for (int i = tid; i < B; i += 256) { l += loc_in[i]; c += conf_in[i]; n += npos_in[i]; }
    for (int off = 32; off; off >>= 1) {
        l += __shfl_down(l, off, 64);
        c += __shfl_down(c, off, 64);
        n += __shfl_down(n, off, 64);
    }
    if (lane == 0) { sl[wv] = l; sc[wv] = c; si[wv] = n; }
    __syncthreads();
    if (tid == 0) {
        float tl = sl[0] + sl[1] + sl[2] + sl[3];
        float tc = sc[0] + sc[1] + sc[2] + sc[3];
        int tn = si[0] + si[1] + si[2] + si[3];
        float fn = (float)tn;
        out[0] = tc / fn + tl / (fn * 4.0f);
    }
}

extern "C" void kernel_launch(void* const* d_in, const int* in_sizes, int n_in,
                              void* d_out, int out_size, void* d_ws, size_t ws_size,
                              hipStream_t stream) {
    const float* plocs   = (const float*)d_in[0];
    const float* pscores = (const float*)d_in[1];
    const float* boxes   = (const float*)d_in[2];
    const float* priors  = (const float*)d_in[3];
    const int B = in_sizes[0] / (NP * 4);

    float* loc_ws  = (float*)d_ws;     // B
    float* conf_ws = loc_ws + B;       // B
    int*   np_ws   = (int*)(conf_ws + B);

    fused_kernel<<<B, BLKS, 0, stream>>>(plocs, pscores, boxes, priors,
                                         loc_ws, conf_ws, np_ws);
    mbox_finalize_kernel<<<1, 256, 0, stream>>>(loc_ws, conf_ws, np_ws, B, (float*)d_out);
}